// Round 1
// baseline (479.861 us; speedup 1.0000x reference)
//
#include <hip/hip_runtime.h>

#define DI __device__ __forceinline__

typedef __attribute__((ext_vector_type(8))) short bh8;
typedef __attribute__((ext_vector_type(4))) float fx4;

DI short f2bf(float f) {
  unsigned u = __builtin_bit_cast(unsigned, f);
  u += 0x7FFFu + ((u >> 16) & 1u);
  return (short)(u >> 16);
}
DI float bf2f(short s) {
  unsigned u = ((unsigned)(unsigned short)s) << 16;
  return __builtin_bit_cast(float, u);
}
DI fx4 mfma16(bh8 a, bh8 b, fx4 c) {
  return __builtin_amdgcn_mfma_f32_16x16x32_bf16(a, b, c, 0, 0, 0);
}
DI fx4 fzero() { fx4 z = {0.f, 0.f, 0.f, 0.f}; return z; }

DI bh8 pack8(const float* src) {
  fx4 v0 = *(const fx4*)src;
  fx4 v1 = *(const fx4*)(src + 4);
  bh8 pk;
#pragma unroll
  for (int j = 0; j < 4; j++) { pk[j] = f2bf(v0[j]); pk[j + 4] = f2bf(v1[j]); }
  return pk;
}
DI bh8 pack8_aff(const float* src, const float* affc) {
  fx4 v0 = *(const fx4*)src;
  fx4 v1 = *(const fx4*)(src + 4);
  bh8 pk;
#pragma unroll
  for (int j = 0; j < 4; j++) {
    pk[j]     = f2bf(v0[j] * affc[2 * j]       + affc[2 * j + 1]);
    pk[j + 4] = f2bf(v1[j] * affc[2 * (j + 4)] + affc[2 * (j + 4) + 1]);
  }
  return pk;
}

// ---------------- holistic LN stats ----------------
__global__ __launch_bounds__(256) void iln_partial(const float* __restrict__ x,
                                                   float* __restrict__ part) {
  const int blk = blockIdx.x, tid = threadIdx.x;
  const fx4* p = (const fx4*)(x + (size_t)blk * 12288);
  float s = 0.f, s2 = 0.f;
#pragma unroll
  for (int i = 0; i < 12; i++) {
    fx4 v = p[i * 256 + tid];
    s  += v[0] + v[1] + v[2] + v[3];
    s2 += v[0] * v[0] + v[1] * v[1] + v[2] * v[2] + v[3] * v[3];
  }
  __shared__ float sm[512];
  sm[tid] = s; sm[256 + tid] = s2;
  __syncthreads();
  for (int st = 128; st > 0; st >>= 1) {
    if (tid < st) { sm[tid] += sm[tid + st]; sm[256 + tid] += sm[256 + tid + st]; }
    __syncthreads();
  }
  if (tid == 0) { part[blk * 2] = sm[0]; part[blk * 2 + 1] = sm[256]; }
}

__global__ __launch_bounds__(256) void iln_final(const float* __restrict__ part,
                                                 const float* __restrict__ w,
                                                 const float* __restrict__ bias,
                                                 float* __restrict__ aff,
                                                 float* __restrict__ st) {
  const int b = blockIdx.x, tid = threadIdx.x;
  __shared__ float sm[512];
  sm[tid]       = part[(b * 256 + tid) * 2];
  sm[256 + tid] = part[(b * 256 + tid) * 2 + 1];
  __syncthreads();
  for (int s = 128; s > 0; s >>= 1) {
    if (tid < s) { sm[tid] += sm[tid + s]; sm[256 + tid] += sm[256 + tid + s]; }
    __syncthreads();
  }
  const float invn = 1.f / 3145728.f;
  float mean = sm[0] * invn;
  float var  = sm[256] * invn - mean * mean;
  float scale = fminf(sqrtf(var + 1e-6f), 2.f);
  if (tid < 192) {
    float a = w[tid] / scale;
    aff[(b * 192 + tid) * 2]     = a;
    aff[(b * 192 + tid) * 2 + 1] = bias[tid] - mean * a;
  }
  if (tid == 0) { st[b * 2] = mean; st[b * 2 + 1] = scale; }
}

// ---------------- QKV GEMM: (32768x192) @ (576x192)^T -> q,k,v bf16 ----------------
__global__ __launch_bounds__(512) void qkv_gemm(const float* __restrict__ x,
                                                const float* __restrict__ aff,
                                                const float* __restrict__ w,
                                                const float* __restrict__ wb,
                                                short* __restrict__ qb,
                                                short* __restrict__ kb,
                                                short* __restrict__ vb) {
  __shared__ short smem[128 * 40 + 192 * 40];
  short* A  = smem;
  short* Bl = smem + 128 * 40;
  const int m0 = blockIdx.x * 128;
  const int n0 = blockIdx.y * 192;
  const int b = m0 >> 14;
  const float* affb = aff + b * 384;
  const int tid = threadIdx.x;
  const int wid = tid >> 6, lane = tid & 63;
  const int g = lane >> 4, h = lane & 15;
  const int wm = wid >> 2, wn = wid & 3;
  const int arow = tid >> 2, apart = tid & 3;
  fx4 acc[4][3];
#pragma unroll
  for (int i = 0; i < 4; i++)
#pragma unroll
    for (int j = 0; j < 3; j++) acc[i][j] = fzero();

  for (int kt = 0; kt < 6; kt++) {
    const int k0 = kt * 32;
    {
      const float* src = x + (size_t)(m0 + arow) * 192 + k0 + apart * 8;
      *(bh8*)&A[arow * 40 + apart * 8] = pack8_aff(src, affb + (k0 + apart * 8) * 2);
    }
    for (int ch = tid; ch < 768; ch += 512) {
      int row = ch >> 2, part = ch & 3;
      const float* src = w + (size_t)(n0 + row) * 192 + k0 + part * 8;
      *(bh8*)&Bl[row * 40 + part * 8] = pack8(src);
    }
    __syncthreads();
    bh8 af[4];
#pragma unroll
    for (int mi = 0; mi < 4; mi++)
      af[mi] = *(bh8*)&A[(wm * 64 + mi * 16 + h) * 40 + g * 8];
#pragma unroll
    for (int ni = 0; ni < 3; ni++) {
      bh8 bf = *(bh8*)&Bl[(wn * 48 + ni * 16 + h) * 40 + g * 8];
#pragma unroll
      for (int mi = 0; mi < 4; mi++) acc[mi][ni] = mfma16(af[mi], bf, acc[mi][ni]);
    }
    __syncthreads();
  }
  short* dst = (blockIdx.y == 0) ? qb : (blockIdx.y == 1 ? kb : vb);
#pragma unroll
  for (int mi = 0; mi < 4; mi++)
#pragma unroll
    for (int ni = 0; ni < 3; ni++)
#pragma unroll
      for (int r = 0; r < 4; r++) {
        int row = m0 + wm * 64 + mi * 16 + g * 4 + r;
        int col = wn * 48 + ni * 16 + h;
        dst[(size_t)row * 192 + col] = f2bf(acc[mi][ni][r] + wb[n0 + col]);
      }
}

// ---------------- attention ----------------
__global__ __launch_bounds__(256) void attn_kernel(const short* __restrict__ qb,
                                                   const short* __restrict__ kb,
                                                   const short* __restrict__ vb,
                                                   const float* __restrict__ rpb,
                                                   short* __restrict__ ao) {
  __shared__ short K_lds[64 * 40];
  __shared__ short Vt_lds[32 * 72];
  __shared__ short P_lds[4 * 64 * 72];
  __shared__ float bias_lds[1521];
  const int tid = threadIdx.x;
  const int win = blockIdx.x, head = blockIdx.y;
  const int b = win >> 6, wy = (win >> 3) & 7, wx = win & 7;
  for (int i = tid; i < 1521; i += 256) bias_lds[i] = rpb[i * 6 + head];
  const int w = tid >> 6, lane = tid & 63, g = lane >> 4, h = lane & 15;
  const float SCALE = 0.1767766952966369f;

  bh8 aq[4];
#pragma unroll
  for (int mi = 0; mi < 4; mi++) {
    int gl = b * 16384 + (wy * 16 + w * 4 + mi) * 128 + wx * 16 + h;
    aq[mi] = *(const bh8*)(qb + (size_t)gl * 192 + head * 32 + g * 8);
  }
  float m_run[4][4], l_run[4][4], corr[4][4];
  fx4 o[4][2];
#pragma unroll
  for (int mi = 0; mi < 4; mi++) {
#pragma unroll
    for (int r = 0; r < 4; r++) { m_run[mi][r] = -1e30f; l_run[mi][r] = 0.f; }
    o[mi][0] = fzero(); o[mi][1] = fzero();
  }
  const int kl_a = tid >> 2, part_a = tid & 3;
  const int kl_b = tid & 63, hg_b = tid >> 6;
  short* Pw = &P_lds[w * 64 * 72];

  for (int kc = 0; kc < 9; kc++) {
    __syncthreads();
    {
      int key = kc * 64 + kl_a;
      int ky = key / 24, kx = key - ky * 24;
      int py = wy * 16 - 4 + ky, px = wx * 16 - 4 + kx;
      bh8 kv = {};
      if (py >= 0 && py < 128 && px >= 0 && px < 128)
        kv = *(const bh8*)(kb + ((size_t)(b * 16384 + py * 128 + px)) * 192 + head * 32 + part_a * 8);
      *(bh8*)&K_lds[kl_a * 40 + part_a * 8] = kv;

      int key2 = kc * 64 + kl_b;
      int ky2 = key2 / 24, kx2 = key2 - ky2 * 24;
      int py2 = wy * 16 - 4 + ky2, px2 = wx * 16 - 4 + kx2;
      bh8 vv = {};
      if (py2 >= 0 && py2 < 128 && px2 >= 0 && px2 < 128)
        vv = *(const bh8*)(vb + ((size_t)(b * 16384 + py2 * 128 + px2)) * 192 + head * 32 + hg_b * 8);
#pragma unroll
      for (int j = 0; j < 8; j++) Vt_lds[(hg_b * 8 + j) * 72 + kl_b] = vv[j];
    }
    __syncthreads();

    fx4 s[4][4];
    bh8 bk[4];
#pragma unroll
    for (int ni = 0; ni < 4; ni++) bk[ni] = *(bh8*)&K_lds[(ni * 16 + h) * 40 + g * 8];
#pragma unroll
    for (int mi = 0; mi < 4; mi++)
#pragma unroll
      for (int ni = 0; ni < 4; ni++) s[mi][ni] = mfma16(aq[mi], bk[ni], fzero());

    int ktn[4];
#pragma unroll
    for (int ni = 0; ni < 4; ni++) {
      int key = kc * 64 + ni * 16 + h;
      int ky = key / 24;
      ktn[ni] = ky * 39 + (key - ky * 24) + 600;
    }
#pragma unroll
    for (int mi = 0; mi < 4; mi++) {
      int qb0 = (w * 4 + mi) * 39 + g * 4;
#pragma unroll
      for (int ni = 0; ni < 4; ni++)
#pragma unroll
        for (int r = 0; r < 4; r++)
          s[mi][ni][r] = s[mi][ni][r] * SCALE + bias_lds[ktn[ni] - qb0 - r];
    }
#pragma unroll
    for (int mi = 0; mi < 4; mi++) {
#pragma unroll
      for (int r = 0; r < 4; r++) {
        float mx = fmaxf(fmaxf(s[mi][0][r], s[mi][1][r]), fmaxf(s[mi][2][r], s[mi][3][r]));
        mx = fmaxf(mx, __shfl_xor(mx, 1));
        mx = fmaxf(mx, __shfl_xor(mx, 2));
        mx = fmaxf(mx, __shfl_xor(mx, 4));
        mx = fmaxf(mx, __shfl_xor(mx, 8));
        float mo = m_run[mi][r];
        float mn = fmaxf(mo, mx);
        float co = __expf(mo - mn);
        m_run[mi][r] = mn;
        corr[mi][r] = co;
        float rs = 0.f;
#pragma unroll
        for (int ni = 0; ni < 4; ni++) {
          float pv = __expf(s[mi][ni][r] - mn);
          s[mi][ni][r] = pv;
          rs += pv;
        }
        rs += __shfl_xor(rs, 1);
        rs += __shfl_xor(rs, 2);
        rs += __shfl_xor(rs, 4);
        rs += __shfl_xor(rs, 8);
        l_run[mi][r] = l_run[mi][r] * co + rs;
      }
    }
#pragma unroll
    for (int mi = 0; mi < 4; mi++)
#pragma unroll
      for (int ni = 0; ni < 4; ni++)
#pragma unroll
        for (int r = 0; r < 4; r++)
          Pw[(mi * 16 + g * 4 + r) * 72 + ni * 16 + h] = f2bf(s[mi][ni][r]);
#pragma unroll
    for (int mi = 0; mi < 4; mi++)
#pragma unroll
      for (int n2 = 0; n2 < 2; n2++) {
        fx4 t = o[mi][n2];
#pragma unroll
        for (int r = 0; r < 4; r++) t[r] *= corr[mi][r];
        o[mi][n2] = t;
      }
#pragma unroll
    for (int ks = 0; ks < 2; ks++) {
      bh8 ap[4];
#pragma unroll
      for (int mi = 0; mi < 4; mi++)
        ap[mi] = *(bh8*)&Pw[(mi * 16 + h) * 72 + ks * 32 + g * 8];
#pragma unroll
      for (int n2 = 0; n2 < 2; n2++) {
        bh8 bv2 = *(bh8*)&Vt_lds[(n2 * 16 + h) * 72 + ks * 32 + g * 8];
#pragma unroll
        for (int mi = 0; mi < 4; mi++) o[mi][n2] = mfma16(ap[mi], bv2, o[mi][n2]);
      }
    }
  }
#pragma unroll
  for (int mi = 0; mi < 4; mi++)
#pragma unroll
    for (int n2 = 0; n2 < 2; n2++)
#pragma unroll
      for (int r = 0; r < 4; r++) {
        float val = o[mi][n2][r] / l_run[mi][r];
        int q = w * 64 + mi * 16 + g * 4 + r;
        ao[((size_t)(win * 256 + q)) * 192 + head * 32 + n2 * 16 + h] = f2bf(val);
      }
}

// ---------------- proj GEMM + window reverse + residual 1 ----------------
__global__ __launch_bounds__(512) void proj_gemm(const short* __restrict__ ao,
                                                 const float* __restrict__ w,
                                                 const float* __restrict__ wb,
                                                 const float* __restrict__ x,
                                                 const float* __restrict__ ls1,
                                                 const float* __restrict__ st,
                                                 float* __restrict__ x1) {
  __shared__ short smem[128 * 40 + 192 * 40];
  short* A  = smem;
  short* Bl = smem + 128 * 40;
  const int m0 = blockIdx.x * 128;
  const int tid = threadIdx.x;
  const int wid = tid >> 6, lane = tid & 63;
  const int g = lane >> 4, h = lane & 15;
  const int wm = wid >> 2, wn = wid & 3;
  const int arow = tid >> 2, apart = tid & 3;
  fx4 acc[4][3];
#pragma unroll
  for (int i = 0; i < 4; i++)
#pragma unroll
    for (int j = 0; j < 3; j++) acc[i][j] = fzero();

  for (int kt = 0; kt < 6; kt++) {
    const int k0 = kt * 32;
    *(bh8*)&A[arow * 40 + apart * 8] =
        *(const bh8*)(ao + (size_t)(m0 + arow) * 192 + k0 + apart * 8);
    for (int ch = tid; ch < 768; ch += 512) {
      int row = ch >> 2, part = ch & 3;
      *(bh8*)&Bl[row * 40 + part * 8] = pack8(w + (size_t)row * 192 + k0 + part * 8);
    }
    __syncthreads();
    bh8 af[4];
#pragma unroll
    for (int mi = 0; mi < 4; mi++)
      af[mi] = *(bh8*)&A[(wm * 64 + mi * 16 + h) * 40 + g * 8];
#pragma unroll
    for (int ni = 0; ni < 3; ni++) {
      bh8 bf = *(bh8*)&Bl[(wn * 48 + ni * 16 + h) * 40 + g * 8];
#pragma unroll
      for (int mi = 0; mi < 4; mi++) acc[mi][ni] = mfma16(af[mi], bf, acc[mi][ni]);
    }
    __syncthreads();
  }
#pragma unroll
  for (int mi = 0; mi < 4; mi++)
#pragma unroll
    for (int ni = 0; ni < 3; ni++)
#pragma unroll
      for (int r = 0; r < 4; r++) {
        int grow = m0 + wm * 64 + mi * 16 + g * 4 + r;
        int win = grow >> 8, q = grow & 255;
        int bb = win >> 6, wy = (win >> 3) & 7, wxx = win & 7;
        int l = (wy * 16 + (q >> 4)) * 128 + wxx * 16 + (q & 15);
        int col = wn * 48 + ni * 16 + h;
        size_t di = ((size_t)(bb * 16384 + l)) * 192 + col;
        float s1 = st[bb * 2 + 1];
        x1[di] = x[di] + s1 * ls1[col] * (acc[mi][ni][r] + wb[col]);
      }
}

// ---------------- fcgv GEMM + SiLU gate -> planar h ----------------
__global__ __launch_bounds__(512) void fcgv_gemm(const float* __restrict__ x1,
                                                 const float* __restrict__ aff,
                                                 const float* __restrict__ w,
                                                 const float* __restrict__ wb,
                                                 short* __restrict__ hp) {
  __shared__ short smem[128 * 40 + 256 * 40];
  short* A  = smem;
  short* Bl = smem + 128 * 40;
  const int m0 = blockIdx.x * 128;
  const int n0 = blockIdx.y * 128;
  const int b = m0 >> 14;
  const int l0 = m0 & 16383;
  const float* affb = aff + b * 384;
  const int tid = threadIdx.x;
  const int wid = tid >> 6, lane = tid & 63;
  const int g = lane >> 4, h = lane & 15;
  const int wm = wid >> 2, wn = wid & 3;
  const int arow = tid >> 2, apart = tid & 3;
  fx4 accg[4][2], accv[4][2];
#pragma unroll
  for (int i = 0; i < 4; i++)
#pragma unroll
    for (int j = 0; j < 2; j++) { accg[i][j] = fzero(); accv[i][j] = fzero(); }

  for (int kt = 0; kt < 6; kt++) {
    const int k0 = kt * 32;
    {
      const float* src = x1 + (size_t)(m0 + arow) * 192 + k0 + apart * 8;
      *(bh8*)&A[arow * 40 + apart * 8] = pack8_aff(src, affb + (k0 + apart * 8) * 2);
    }
    for (int ch = tid; ch < 1024; ch += 512) {
      int row = ch >> 2, part = ch & 3;
      int wrow = (row < 128) ? (n0 + row) : (512 + n0 + row - 128);
      *(bh8*)&Bl[row * 40 + part * 8] = pack8(w + (size_t)wrow * 192 + k0 + part * 8);
    }
    __syncthreads();
    bh8 af[4];
#pragma unroll
    for (int mi = 0; mi < 4; mi++)
      af[mi] = *(bh8*)&A[(wm * 64 + mi * 16 + h) * 40 + g * 8];
#pragma unroll
    for (int ni = 0; ni < 2; ni++) {
      bh8 bg = *(bh8*)&Bl[(wn * 32 + ni * 16 + h) * 40 + g * 8];
      bh8 bv = *(bh8*)&Bl[(128 + wn * 32 + ni * 16 + h) * 40 + g * 8];
#pragma unroll
      for (int mi = 0; mi < 4; mi++) {
        accg[mi][ni] = mfma16(af[mi], bg, accg[mi][ni]);
        accv[mi][ni] = mfma16(af[mi], bv, accv[mi][ni]);
      }
    }
    __syncthreads();
  }
  short hs[4][2][4];
#pragma unroll
  for (int mi = 0; mi < 4; mi++)
#pragma unroll
    for (int ni = 0; ni < 2; ni++)
#pragma unroll
      for (int r = 0; r < 4; r++) {
        int colg = n0 + wn * 32 + ni * 16 + h;
        float gv = accg[mi][ni][r] + wb[colg];
        float vv = accv[mi][ni][r] + wb[512 + colg];
        float hval = gv / (1.f + __expf(-gv)) * vv;
        hs[mi][ni][r] = f2bf(hval);
      }
  short* T = smem;  // 64*136 = 8704 shorts, fits
  for (int p = 0; p < 2; p++) {
    if ((wn >> 1) == p) {
#pragma unroll
      for (int mi = 0; mi < 4; mi++)
#pragma unroll
        for (int ni = 0; ni < 2; ni++)
#pragma unroll
          for (int r = 0; r < 4; r++) {
            int c = (wn & 1) * 32 + ni * 16 + h;
            int rl = wm * 64 + mi * 16 + g * 4 + r;
            T[c * 136 + rl] = hs[mi][ni][r];
          }
    }
    __syncthreads();
    for (int ch = tid; ch < 1024; ch += 512) {
      int c = ch >> 4, lg = ch & 15;
      bh8 v = *(bh8*)&T[c * 136 + lg * 8];
      *(bh8*)(hp + (((size_t)(b * 512 + n0 + p * 64 + c)) << 14) + l0 + lg * 8) = v;
    }
    __syncthreads();
  }
}

// ---------------- depthwise convs (planar) ----------------
__global__ __launch_bounds__(256) void dwconv_d1(const short* __restrict__ in,
                                                 const float* __restrict__ w9,
                                                 const float* __restrict__ bias,
                                                 short* __restrict__ outp) {
  const int p = blockIdx.y, c = p & 511;
  const int y = blockIdx.x * 2 + (threadIdx.x >> 7);
  const int x = threadIdx.x & 127;
  const short* ip = in + ((size_t)p << 14);
  float acc = bias[c];
#pragma unroll
  for (int ky = 0; ky < 3; ky++) {
    int yy = y + ky - 1;
    if (yy < 0 || yy > 127) continue;
#pragma unroll
    for (int kx = 0; kx < 3; kx++) {
      int xx = x + kx - 1;
      if (xx < 0 || xx > 127) continue;
      acc += bf2f(ip[yy * 128 + xx]) * w9[c * 9 + ky * 3 + kx];
    }
  }
  outp[((size_t)p << 14) + y * 128 + x] = f2bf(acc);
}

__global__ __launch_bounds__(256) void dwconv_d2(const short* __restrict__ in,
                                                 const float* __restrict__ w9,
                                                 const float* __restrict__ bias,
                                                 const float* __restrict__ dscale,
                                                 short* __restrict__ outp) {
  const int p = blockIdx.y, c = p & 511;
  const int y = blockIdx.x * 2 + (threadIdx.x >> 7);
  const int x = threadIdx.x & 127;
  const short* ip = in + ((size_t)p << 14);
  float acc = bias[c];
#pragma unroll
  for (int ky = 0; ky < 3; ky++) {
    int yy = y + (ky - 1) * 2;
    if (yy < 0 || yy > 127) continue;
#pragma unroll
    for (int kx = 0; kx < 3; kx++) {
      int xx = x + (kx - 1) * 2;
      if (xx < 0 || xx > 127) continue;
      acc += bf2f(ip[yy * 128 + xx]) * w9[c * 9 + ky * 3 + kx];
    }
  }
  float center = bf2f(ip[y * 128 + x]);
  outp[((size_t)p << 14) + y * 128 + x] = f2bf(center + dscale[0] * acc);
}

// ---------------- fco GEMM + residual 2 -> out ----------------
__global__ __launch_bounds__(512) void fco_gemm(const short* __restrict__ h2,
                                                const float* __restrict__ w,
                                                const float* __restrict__ wb,
                                                const float* __restrict__ x1,
                                                const float* __restrict__ ls2,
                                                const float* __restrict__ st,
                                                float* __restrict__ out) {
  __shared__ short smem[128 * 40 + 192 * 40];
  short* A  = smem;
  short* Bl = smem + 128 * 40;
  const int m0 = blockIdx.x * 128;
  const int b = m0 >> 14;
  const int l0 = m0 & 16383;
  const int tid = threadIdx.x;
  const int wid = tid >> 6, lane = tid & 63;
  const int g = lane >> 4, h = lane & 15;
  const int wm = wid >> 2, wn = wid & 3;
  fx4 acc[4][3];
#pragma unroll
  for (int i = 0; i < 4; i++)
#pragma unroll
    for (int j = 0; j < 3; j++) acc[i][j] = fzero();

  for (int kt = 0; kt < 16; kt++) {
    const int k0 = kt * 32;
    {
      int c = tid & 31, lg = tid >> 5;
      const short* src = h2 + (((size_t)(b * 512 + k0 + c)) << 14) + l0 + lg * 8;
      bh8 v = *(const bh8*)src;
#pragma unroll
      for (int j = 0; j < 8; j++) A[(lg * 8 + j) * 40 + c] = v[j];
    }
    for (int ch = tid; ch < 768; ch += 512) {
      int row = ch >> 2, part = ch & 3;
      *(bh8*)&Bl[row * 40 + part * 8] = pack8(w + (size_t)row * 512 + k0 + part * 8);
    }
    __syncthreads();
    bh8 af[4];
#pragma unroll
    for (int mi = 0; mi < 4; mi++)
      af[mi] = *(bh8*)&A[(wm * 64 + mi * 16 + h) * 40 + g * 8];
#pragma unroll
    for (int ni = 0; ni < 3; ni++) {
      bh8 bf = *(bh8*)&Bl[(wn * 48 + ni * 16 + h) * 40 + g * 8];
#pragma unroll
      for (int mi = 0; mi < 4; mi++) acc[mi][ni] = mfma16(af[mi], bf, acc[mi][ni]);
    }
    __syncthreads();
  }
  float s2 = st[b * 2 + 1];
#pragma unroll
  for (int mi = 0; mi < 4; mi++)
#pragma unroll
    for (int ni = 0; ni < 3; ni++)
#pragma unroll
      for (int r = 0; r < 4; r++) {
        int row = m0 + wm * 64 + mi * 16 + g * 4 + r;
        int col = wn * 48 + ni * 16 + h;
        size_t di = (size_t)row * 192 + col;
        out[di] = x1[di] + s2 * ls2[col] * (acc[mi][ni][r] + wb[col]);
      }
}

extern "C" void kernel_launch(void* const* d_in, const int* in_sizes, int n_in,
                              void* d_out, int out_size, void* d_ws, size_t ws_size,
                              hipStream_t stream) {
  const float* x      = (const float*)d_in[0];
  const float* qkv_w  = (const float*)d_in[1];
  const float* qkv_b  = (const float*)d_in[2];
  const float* proj_w = (const float*)d_in[3];
  const float* proj_b = (const float*)d_in[4];
  const float* rpb    = (const float*)d_in[5];
  const float* n1_w   = (const float*)d_in[6];
  const float* n1_b   = (const float*)d_in[7];
  const float* ls1    = (const float*)d_in[8];
  const float* n2_w   = (const float*)d_in[9];
  const float* n2_b   = (const float*)d_in[10];
  const float* ls2    = (const float*)d_in[11];
  const float* fcgv_w = (const float*)d_in[12];
  const float* fcgv_b = (const float*)d_in[13];
  const float* dw_w   = (const float*)d_in[14];
  const float* dw_b   = (const float*)d_in[15];
  const float* dwd_w  = (const float*)d_in[16];
  const float* dwd_b  = (const float*)d_in[17];
  const float* dil    = (const float*)d_in[18];
  const float* fco_w  = (const float*)d_in[19];
  const float* fco_b  = (const float*)d_in[20];
  float* out = (float*)d_out;
  char* ws = (char*)d_ws;

  // workspace layout (aliased; all offsets 16B-aligned). total ~92.3 MB
  short* qb  = (short*)(ws + 0);          // 12.58 MB  (dead after attn)
  short* kb  = (short*)(ws + 12582912);   // 12.58 MB  (dead after attn)
  short* vb  = (short*)(ws + 25165824);   // 12.58 MB  (dead after attn)
  short* ao  = (short*)(ws + 37748736);   // 12.58 MB  (dead after proj)
  float* x1  = (float*)(ws + 0);          // 25.17 MB  (over qb+kb)
  short* hp  = (short*)(ws + 25165824);   // 33.55 MB  (over vb+ao)
  short* y1  = (short*)(ws + 58720256);   // 33.55 MB
  short* h2  = (short*)(ws + 25165824);   // 33.55 MB  (over hp, dead after conv1)
  float* part = (float*)(ws + 92274688);
  float* aff1 = (float*)(ws + 92278784);
  float* aff2 = (float*)(ws + 92281856);
  float* st1  = (float*)(ws + 92284928);
  float* st2  = (float*)(ws + 92284944);

  iln_partial<<<512, 256, 0, stream>>>(x, part);
  iln_final<<<2, 256, 0, stream>>>(part, n1_w, n1_b, aff1, st1);
  qkv_gemm<<<dim3(256, 3), 512, 0, stream>>>(x, aff1, qkv_w, qkv_b, qb, kb, vb);
  attn_kernel<<<dim3(128, 6), 256, 0, stream>>>(qb, kb, vb, rpb, ao);
  proj_gemm<<<dim3(256), 512, 0, stream>>>(ao, proj_w, proj_b, x, ls1, st1, x1);
  iln_partial<<<512, 256, 0, stream>>>(x1, part);
  iln_final<<<2, 256, 0, stream>>>(part, n2_w, n2_b, aff2, st2);
  fcgv_gemm<<<dim3(256, 4), 512, 0, stream>>>(x1, aff2, fcgv_w, fcgv_b, hp);
  dwconv_d1<<<dim3(64, 1024), 256, 0, stream>>>(hp, dw_w, dw_b, y1);
  dwconv_d2<<<dim3(64, 1024), 256, 0, stream>>>(y1, dwd_w, dwd_b, dil, h2);
  fco_gemm<<<dim3(256), 512, 0, stream>>>(h2, fco_w, fco_b, x1, ls2, st2, out);
}

// Round 2
// 385.696 us; speedup vs baseline: 1.2441x; 1.2441x over previous
//
#include <hip/hip_runtime.h>

#define DI __device__ __forceinline__

typedef __attribute__((ext_vector_type(8))) short bh8;
typedef __attribute__((ext_vector_type(4))) float fx4;
typedef __attribute__((ext_vector_type(16))) float fx16;

DI short f2bf(float f) {
  unsigned u = __builtin_bit_cast(unsigned, f);
  u += 0x7FFFu + ((u >> 16) & 1u);
  return (short)(u >> 16);
}
DI float bf2f(short s) {
  unsigned u = ((unsigned)(unsigned short)s) << 16;
  return __builtin_bit_cast(float, u);
}
DI fx4 mfma16(bh8 a, bh8 b, fx4 c) {
  return __builtin_amdgcn_mfma_f32_16x16x32_bf16(a, b, c, 0, 0, 0);
}
DI fx16 mfma32(bh8 a, bh8 b, fx16 c) {
  return __builtin_amdgcn_mfma_f32_32x32x16_bf16(a, b, c, 0, 0, 0);
}
DI fx4 fzero() { fx4 z = {0.f, 0.f, 0.f, 0.f}; return z; }

DI bh8 pack8(const float* src) {
  fx4 v0 = *(const fx4*)src;
  fx4 v1 = *(const fx4*)(src + 4);
  bh8 pk;
#pragma unroll
  for (int j = 0; j < 4; j++) { pk[j] = f2bf(v0[j]); pk[j + 4] = f2bf(v1[j]); }
  return pk;
}
DI bh8 pack8_aff(const float* src, const float* affc) {
  fx4 v0 = *(const fx4*)src;
  fx4 v1 = *(const fx4*)(src + 4);
  bh8 pk;
#pragma unroll
  for (int j = 0; j < 4; j++) {
    pk[j]     = f2bf(v0[j] * affc[2 * j]       + affc[2 * j + 1]);
    pk[j + 4] = f2bf(v1[j] * affc[2 * (j + 4)] + affc[2 * (j + 4) + 1]);
  }
  return pk;
}

// ---------------- holistic LN stats ----------------
__global__ __launch_bounds__(256) void iln_partial(const float* __restrict__ x,
                                                   float* __restrict__ part) {
  const int blk = blockIdx.x, tid = threadIdx.x;
  const fx4* p = (const fx4*)(x + (size_t)blk * 12288);
  float s = 0.f, s2 = 0.f;
#pragma unroll
  for (int i = 0; i < 12; i++) {
    fx4 v = p[i * 256 + tid];
    s  += v[0] + v[1] + v[2] + v[3];
    s2 += v[0] * v[0] + v[1] * v[1] + v[2] * v[2] + v[3] * v[3];
  }
  __shared__ float sm[512];
  sm[tid] = s; sm[256 + tid] = s2;
  __syncthreads();
  for (int st = 128; st > 0; st >>= 1) {
    if (tid < st) { sm[tid] += sm[tid + st]; sm[256 + tid] += sm[256 + tid + st]; }
    __syncthreads();
  }
  if (tid == 0) { part[blk * 2] = sm[0]; part[blk * 2 + 1] = sm[256]; }
}

__global__ __launch_bounds__(256) void iln_final(const float* __restrict__ part,
                                                 const float* __restrict__ w,
                                                 const float* __restrict__ bias,
                                                 float* __restrict__ aff,
                                                 float* __restrict__ st) {
  const int b = blockIdx.x, tid = threadIdx.x;
  __shared__ float sm[512];
  sm[tid]       = part[(b * 256 + tid) * 2];
  sm[256 + tid] = part[(b * 256 + tid) * 2 + 1];
  __syncthreads();
  for (int s = 128; s > 0; s >>= 1) {
    if (tid < s) { sm[tid] += sm[tid + s]; sm[256 + tid] += sm[256 + tid + s]; }
    __syncthreads();
  }
  const float invn = 1.f / 3145728.f;
  float mean = sm[0] * invn;
  float var  = sm[256] * invn - mean * mean;
  float scale = fminf(sqrtf(var + 1e-6f), 2.f);
  if (tid < 192) {
    float a = w[tid] / scale;
    aff[(b * 192 + tid) * 2]     = a;
    aff[(b * 192 + tid) * 2 + 1] = bias[tid] - mean * a;
  }
  if (tid == 0) { st[b * 2] = mean; st[b * 2 + 1] = scale; }
}

// ---------------- bias table gen: acc-register layout, bf16, pre-divided by SCALE ----------------
// layout: [head][w 4][kc 9][ki 2][qi 2][lane 64][r 16]
__global__ __launch_bounds__(256) void bias_gen(const float* __restrict__ rpb,
                                                short* __restrict__ bt) {
  int t = blockIdx.x * 256 + threadIdx.x;  // 55296 threads
  int lane = t & 63;
  int u = t >> 6;
  int qi = u & 1; u >>= 1;
  int ki = u & 1; u >>= 1;
  int kc = u % 9; u = u / 9;
  int w = u & 3, head = u >> 2;
  int c = lane & 31, hi = lane >> 5;
  int q = w * 64 + qi * 32 + c;
  int qterm = (q >> 4) * 39 + (q & 15);
  short o[16];
#pragma unroll
  for (int r = 0; r < 16; r++) {
    int k = kc * 64 + ki * 32 + (r & 3) + 8 * (r >> 2) + 4 * hi;
    int ky = (k * 2731) >> 16;                 // k/24 for k<600
    int kx = k - ky * 24;
    int idx = ky * 39 + kx + 600 - qterm;      // (ky-qy+15)*39 + (kx-qx+15)
    o[r] = f2bf(rpb[idx * 6 + head] * 5.656854249492381f);  // bias / SCALE
  }
  *(bh8*)(bt + (size_t)t * 16)     = *(bh8*)&o[0];
  *(bh8*)(bt + (size_t)t * 16 + 8) = *(bh8*)&o[8];
}

// ---------------- QKV GEMM: (32768x192) @ (576x192)^T -> q,k,v bf16 ----------------
__global__ __launch_bounds__(512) void qkv_gemm(const float* __restrict__ x,
                                                const float* __restrict__ aff,
                                                const float* __restrict__ w,
                                                const float* __restrict__ wb,
                                                short* __restrict__ qb,
                                                short* __restrict__ kb,
                                                short* __restrict__ vb) {
  __shared__ short smem[128 * 40 + 192 * 40];
  short* A  = smem;
  short* Bl = smem + 128 * 40;
  const int m0 = blockIdx.x * 128;
  const int n0 = blockIdx.y * 192;
  const int b = m0 >> 14;
  const float* affb = aff + b * 384;
  const int tid = threadIdx.x;
  const int wid = tid >> 6, lane = tid & 63;
  const int g = lane >> 4, h = lane & 15;
  const int wm = wid >> 2, wn = wid & 3;
  const int arow = tid >> 2, apart = tid & 3;
  fx4 acc[4][3];
#pragma unroll
  for (int i = 0; i < 4; i++)
#pragma unroll
    for (int j = 0; j < 3; j++) acc[i][j] = fzero();

  for (int kt = 0; kt < 6; kt++) {
    const int k0 = kt * 32;
    {
      const float* src = x + (size_t)(m0 + arow) * 192 + k0 + apart * 8;
      *(bh8*)&A[arow * 40 + apart * 8] = pack8_aff(src, affb + (k0 + apart * 8) * 2);
    }
    for (int ch = tid; ch < 768; ch += 512) {
      int row = ch >> 2, part = ch & 3;
      const float* src = w + (size_t)(n0 + row) * 192 + k0 + part * 8;
      *(bh8*)&Bl[row * 40 + part * 8] = pack8(src);
    }
    __syncthreads();
    bh8 af[4];
#pragma unroll
    for (int mi = 0; mi < 4; mi++)
      af[mi] = *(bh8*)&A[(wm * 64 + mi * 16 + h) * 40 + g * 8];
#pragma unroll
    for (int ni = 0; ni < 3; ni++) {
      bh8 bf = *(bh8*)&Bl[(wn * 48 + ni * 16 + h) * 40 + g * 8];
#pragma unroll
      for (int mi = 0; mi < 4; mi++) acc[mi][ni] = mfma16(af[mi], bf, acc[mi][ni]);
    }
    __syncthreads();
  }
  short* dst = (blockIdx.y == 0) ? qb : (blockIdx.y == 1 ? kb : vb);
#pragma unroll
  for (int mi = 0; mi < 4; mi++)
#pragma unroll
    for (int ni = 0; ni < 3; ni++)
#pragma unroll
      for (int r = 0; r < 4; r++) {
        int row = m0 + wm * 64 + mi * 16 + g * 4 + r;
        int col = wn * 48 + ni * 16 + h;
        dst[(size_t)row * 192 + col] = f2bf(acc[mi][ni][r] + wb[n0 + col]);
      }
}

// ---------------- attention: swapped-QK 32x32 MFMA, in-register P, no max ----------------
__global__ __launch_bounds__(256, 3) void attn_kernel(const short* __restrict__ qb,
                                                      const short* __restrict__ kb,
                                                      const short* __restrict__ vb,
                                                      const short* __restrict__ bt,
                                                      short* __restrict__ ao) {
  __shared__ short K_lds[64 * 40];   // [k 64][d 32 pad 40]  (stride 80B: 5 odd -> conflict-free b128)
  __shared__ short Vt_lds[32 * 72];  // [d 32][k 64 pad 72]  (stride 144B: 9 odd -> conflict-free b128)
  __shared__ float l_lds[256];
  const int tid = threadIdx.x;
  const int win = blockIdx.x, head = blockIdx.y;
  const int b = win >> 6, wy = (win >> 3) & 7, wx = win & 7;
  const int w = tid >> 6, lane = tid & 63, c = lane & 31, hi = lane >> 5;
  const float SCALE = 0.1767766952966369f;

  // Q fragments (B-operand of swapped QK): qf[qi][ds] ; q row = w*64 + qi*32 + c
  bh8 qf[2][2];
#pragma unroll
  for (int qi = 0; qi < 2; qi++) {
    int ql = w * 64 + qi * 32 + c;
    size_t gl = (size_t)(b * 16384 + (wy * 16 + (ql >> 4)) * 128 + wx * 16 + (ql & 15));
#pragma unroll
    for (int ds = 0; ds < 2; ds++)
      qf[qi][ds] = *(const bh8*)(qb + gl * 192 + head * 32 + ds * 16 + hi * 8);
  }
  float l_run[2] = {0.f, 0.f};
  fx16 out[2];
#pragma unroll
  for (int r = 0; r < 16; r++) { out[0][r] = 0.f; out[1][r] = 0.f; }

  const short* btw = bt + (size_t)(head * 4 + w) * 36864;

  const int kl_a = tid >> 2, part_a = tid & 3;
  const int kl_b = tid & 63, hg_b = tid >> 6;

  for (int kc = 0; kc < 9; kc++) {
    __syncthreads();
    {
      int key = kc * 64 + kl_a;
      int ky = key / 24, kx = key - ky * 24;
      int py = wy * 16 - 4 + ky, px = wx * 16 - 4 + kx;
      bh8 kv = {};
      if ((unsigned)py < 128u && (unsigned)px < 128u)
        kv = *(const bh8*)(kb + ((size_t)(b * 16384 + py * 128 + px)) * 192 + head * 32 + part_a * 8);
      *(bh8*)&K_lds[kl_a * 40 + part_a * 8] = kv;

      int key2 = kc * 64 + kl_b;
      int ky2 = key2 / 24, kx2 = key2 - ky2 * 24;
      int py2 = wy * 16 - 4 + ky2, px2 = wx * 16 - 4 + kx2;
      bh8 vv = {};
      if ((unsigned)py2 < 128u && (unsigned)px2 < 128u)
        vv = *(const bh8*)(vb + ((size_t)(b * 16384 + py2 * 128 + px2)) * 192 + head * 32 + hg_b * 8);
#pragma unroll
      for (int j = 0; j < 8; j++) Vt_lds[(hg_b * 8 + j) * 72 + kl_b] = vv[j];
    }
    __syncthreads();

#pragma unroll
    for (int ki = 0; ki < 2; ki++) {
      // accumulators init from bias table (already /SCALE); st[qi][r] will become
      // S^T: value for q = qi*32+c, k = 64kc + 32ki + (r&3)+8*(r>>2)+4*hi
      fx16 st[2];
#pragma unroll
      for (int qi = 0; qi < 2; qi++) {
        const short* bp = btw + (((kc * 2 + ki) * 2 + qi) * 64 + lane) * 16;
        int4 b0 = *(const int4*)bp;
        int4 b1 = *(const int4*)(bp + 8);
#pragma unroll
        for (int d2 = 0; d2 < 4; d2++) {
          unsigned u0 = ((const unsigned*)&b0)[d2];
          unsigned u1 = ((const unsigned*)&b1)[d2];
          st[qi][d2 * 2]     = __builtin_bit_cast(float, u0 << 16);
          st[qi][d2 * 2 + 1] = __builtin_bit_cast(float, u0 & 0xffff0000u);
          st[qi][8 + d2 * 2]     = __builtin_bit_cast(float, u1 << 16);
          st[qi][8 + d2 * 2 + 1] = __builtin_bit_cast(float, u1 & 0xffff0000u);
        }
      }
      // QK: S^T[k][q] = sum_d K[k][d] Q[q][d]
#pragma unroll
      for (int ds = 0; ds < 2; ds++) {
        bh8 kf = *(bh8*)&K_lds[(ki * 32 + c) * 40 + ds * 16 + hi * 8];
        st[0] = mfma32(kf, qf[0][ds], st[0]);
        st[1] = mfma32(kf, qf[1][ds], st[1]);
      }
      // p = exp(s*SCALE) (no max-sub: |logits| << 1 for this model scale); row-sum
#pragma unroll
      for (int qi = 0; qi < 2; qi++) {
        float s = 0.f;
#pragma unroll
        for (int r = 0; r < 16; r++) {
          float p = __expf(st[qi][r] * SCALE);
          st[qi][r] = p;
          s += p;
        }
        l_run[qi] += s;
      }
      // Build PV A-fragments: pa[qi][k1] covers k = 64kc + (2ki+k1)*16 + 8hi + j.
      // dword dd of frag: j=2dd,2dd+1 -> source reg r = 2(dd&1)+8k1 (+4 if target hi=1),
      // source lane hi_s = dd>>1 -> half-exchange via shfl_xor(32)+select.
      int dwq[2][2][4];
#pragma unroll
      for (int qi = 0; qi < 2; qi++)
#pragma unroll
        for (int k1 = 0; k1 < 2; k1++)
#pragma unroll
          for (int p01 = 0; p01 < 2; p01++) {
            int rA = 2 * p01 + 8 * k1;
            int A, Bv;
            asm("v_cvt_pk_bf16_f32 %0, %1, %2" : "=v"(A)  : "v"(st[qi][rA]),     "v"(st[qi][rA + 1]));
            asm("v_cvt_pk_bf16_f32 %0, %1, %2" : "=v"(Bv) : "v"(st[qi][rA + 4]), "v"(st[qi][rA + 5]));
            int Ax = __shfl_xor(A, 32);
            int Bx = __shfl_xor(Bv, 32);
            dwq[qi][k1][p01]     = hi ? Bx : A;   // lanes hi=0: own A; hi=1: partner's B
            dwq[qi][k1][p01 + 2] = hi ? Bv : Ax;  // lanes hi=0: partner's A; hi=1: own B
          }
      // PV: out[q][d] += P[q][k] V[k][d]
#pragma unroll
      for (int k1 = 0; k1 < 2; k1++) {
        bh8 bv2 = *(bh8*)&Vt_lds[c * 72 + (ki * 2 + k1) * 16 + hi * 8];
#pragma unroll
        for (int qi = 0; qi < 2; qi++) {
          int4 t4 = {dwq[qi][k1][0], dwq[qi][k1][1], dwq[qi][k1][2], dwq[qi][k1][3]};
          out[qi] = mfma32(__builtin_bit_cast(bh8, t4), bv2, out[qi]);
        }
      }
    }
  }
  // finalize: l per q -> reciprocal via small LDS redistribute
#pragma unroll
  for (int qi = 0; qi < 2; qi++) {
    float lp = l_run[qi] + __shfl_xor(l_run[qi], 32);
    l_lds[w * 64 + qi * 32 + c] = 1.f / lp;
  }
  __syncthreads();
#pragma unroll
  for (int qi = 0; qi < 2; qi++)
#pragma unroll
    for (int r = 0; r < 16; r++) {
      int row = (r & 3) + 8 * (r >> 2) + 4 * hi;
      float val = out[qi][r] * l_lds[w * 64 + qi * 32 + row];
      int ql = w * 64 + qi * 32 + row;
      ao[((size_t)(win * 256 + ql)) * 192 + head * 32 + c] = f2bf(val);
    }
}

// ---------------- proj GEMM + window reverse + residual 1 ----------------
__global__ __launch_bounds__(512) void proj_gemm(const short* __restrict__ ao,
                                                 const float* __restrict__ w,
                                                 const float* __restrict__ wb,
                                                 const float* __restrict__ x,
                                                 const float* __restrict__ ls1,
                                                 const float* __restrict__ st,
                                                 float* __restrict__ x1) {
  __shared__ short smem[128 * 40 + 192 * 40];
  short* A  = smem;
  short* Bl = smem + 128 * 40;
  const int m0 = blockIdx.x * 128;
  const int tid = threadIdx.x;
  const int wid = tid >> 6, lane = tid & 63;
  const int g = lane >> 4, h = lane & 15;
  const int wm = wid >> 2, wn = wid & 3;
  const int arow = tid >> 2, apart = tid & 3;
  fx4 acc[4][3];
#pragma unroll
  for (int i = 0; i < 4; i++)
#pragma unroll
    for (int j = 0; j < 3; j++) acc[i][j] = fzero();

  for (int kt = 0; kt < 6; kt++) {
    const int k0 = kt * 32;
    *(bh8*)&A[arow * 40 + apart * 8] =
        *(const bh8*)(ao + (size_t)(m0 + arow) * 192 + k0 + apart * 8);
    for (int ch = tid; ch < 768; ch += 512) {
      int row = ch >> 2, part = ch & 3;
      *(bh8*)&Bl[row * 40 + part * 8] = pack8(w + (size_t)row * 192 + k0 + part * 8);
    }
    __syncthreads();
    bh8 af[4];
#pragma unroll
    for (int mi = 0; mi < 4; mi++)
      af[mi] = *(bh8*)&A[(wm * 64 + mi * 16 + h) * 40 + g * 8];
#pragma unroll
    for (int ni = 0; ni < 3; ni++) {
      bh8 bf = *(bh8*)&Bl[(wn * 48 + ni * 16 + h) * 40 + g * 8];
#pragma unroll
      for (int mi = 0; mi < 4; mi++) acc[mi][ni] = mfma16(af[mi], bf, acc[mi][ni]);
    }
    __syncthreads();
  }
#pragma unroll
  for (int mi = 0; mi < 4; mi++)
#pragma unroll
    for (int ni = 0; ni < 3; ni++)
#pragma unroll
      for (int r = 0; r < 4; r++) {
        int grow = m0 + wm * 64 + mi * 16 + g * 4 + r;
        int win = grow >> 8, q = grow & 255;
        int bb = win >> 6, wy = (win >> 3) & 7, wxx = win & 7;
        int l = (wy * 16 + (q >> 4)) * 128 + wxx * 16 + (q & 15);
        int col = wn * 48 + ni * 16 + h;
        size_t di = ((size_t)(bb * 16384 + l)) * 192 + col;
        float s1 = st[bb * 2 + 1];
        x1[di] = x[di] + s1 * ls1[col] * (acc[mi][ni][r] + wb[col]);
      }
}

// ---------------- fcgv GEMM + SiLU gate -> planar h ----------------
__global__ __launch_bounds__(512) void fcgv_gemm(const float* __restrict__ x1,
                                                 const float* __restrict__ aff,
                                                 const float* __restrict__ w,
                                                 const float* __restrict__ wb,
                                                 short* __restrict__ hp) {
  __shared__ short smem[128 * 40 + 256 * 40];
  short* A  = smem;
  short* Bl = smem + 128 * 40;
  const int m0 = blockIdx.x * 128;
  const int n0 = blockIdx.y * 128;
  const int b = m0 >> 14;
  const int l0 = m0 & 16383;
  const float* affb = aff + b * 384;
  const int tid = threadIdx.x;
  const int wid = tid >> 6, lane = tid & 63;
  const int g = lane >> 4, h = lane & 15;
  const int wm = wid >> 2, wn = wid & 3;
  const int arow = tid >> 2, apart = tid & 3;
  fx4 accg[4][2], accv[4][2];
#pragma unroll
  for (int i = 0; i < 4; i++)
#pragma unroll
    for (int j = 0; j < 2; j++) { accg[i][j] = fzero(); accv[i][j] = fzero(); }

  for (int kt = 0; kt < 6; kt++) {
    const int k0 = kt * 32;
    {
      const float* src = x1 + (size_t)(m0 + arow) * 192 + k0 + apart * 8;
      *(bh8*)&A[arow * 40 + apart * 8] = pack8_aff(src, affb + (k0 + apart * 8) * 2);
    }
    for (int ch = tid; ch < 1024; ch += 512) {
      int row = ch >> 2, part = ch & 3;
      int wrow = (row < 128) ? (n0 + row) : (512 + n0 + row - 128);
      *(bh8*)&Bl[row * 40 + part * 8] = pack8(w + (size_t)wrow * 192 + k0 + part * 8);
    }
    __syncthreads();
    bh8 af[4];
#pragma unroll
    for (int mi = 0; mi < 4; mi++)
      af[mi] = *(bh8*)&A[(wm * 64 + mi * 16 + h) * 40 + g * 8];
#pragma unroll
    for (int ni = 0; ni < 2; ni++) {
      bh8 bg = *(bh8*)&Bl[(wn * 32 + ni * 16 + h) * 40 + g * 8];
      bh8 bv = *(bh8*)&Bl[(128 + wn * 32 + ni * 16 + h) * 40 + g * 8];
#pragma unroll
      for (int mi = 0; mi < 4; mi++) {
        accg[mi][ni] = mfma16(af[mi], bg, accg[mi][ni]);
        accv[mi][ni] = mfma16(af[mi], bv, accv[mi][ni]);
      }
    }
    __syncthreads();
  }
  short hs[4][2][4];
#pragma unroll
  for (int mi = 0; mi < 4; mi++)
#pragma unroll
    for (int ni = 0; ni < 2; ni++)
#pragma unroll
      for (int r = 0; r < 4; r++) {
        int colg = n0 + wn * 32 + ni * 16 + h;
        float gv = accg[mi][ni][r] + wb[colg];
        float vv = accv[mi][ni][r] + wb[512 + colg];
        float hval = gv / (1.f + __expf(-gv)) * vv;
        hs[mi][ni][r] = f2bf(hval);
      }
  short* T = smem;  // 64*136 = 8704 shorts, fits
  for (int p = 0; p < 2; p++) {
    if ((wn >> 1) == p) {
#pragma unroll
      for (int mi = 0; mi < 4; mi++)
#pragma unroll
        for (int ni = 0; ni < 2; ni++)
#pragma unroll
          for (int r = 0; r < 4; r++) {
            int cc = (wn & 1) * 32 + ni * 16 + h;
            int rl = wm * 64 + mi * 16 + g * 4 + r;
            T[cc * 136 + rl] = hs[mi][ni][r];
          }
    }
    __syncthreads();
    for (int ch = tid; ch < 1024; ch += 512) {
      int cc = ch >> 4, lg = ch & 15;
      bh8 v = *(bh8*)&T[cc * 136 + lg * 8];
      *(bh8*)(hp + (((size_t)(b * 512 + n0 + p * 64 + cc)) << 14) + l0 + lg * 8) = v;
    }
    __syncthreads();
  }
}

// ---------------- depthwise convs (planar) ----------------
__global__ __launch_bounds__(256) void dwconv_d1(const short* __restrict__ in,
                                                 const float* __restrict__ w9,
                                                 const float* __restrict__ bias,
                                                 short* __restrict__ outp) {
  const int p = blockIdx.y, c = p & 511;
  const int y = blockIdx.x * 2 + (threadIdx.x >> 7);
  const int x = threadIdx.x & 127;
  const short* ip = in + ((size_t)p << 14);
  float acc = bias[c];
#pragma unroll
  for (int ky = 0; ky < 3; ky++) {
    int yy = y + ky - 1;
    if (yy < 0 || yy > 127) continue;
#pragma unroll
    for (int kx = 0; kx < 3; kx++) {
      int xx = x + kx - 1;
      if (xx < 0 || xx > 127) continue;
      acc += bf2f(ip[yy * 128 + xx]) * w9[c * 9 + ky * 3 + kx];
    }
  }
  outp[((size_t)p << 14) + y * 128 + x] = f2bf(acc);
}

__global__ __launch_bounds__(256) void dwconv_d2(const short* __restrict__ in,
                                                 const float* __restrict__ w9,
                                                 const float* __restrict__ bias,
                                                 const float* __restrict__ dscale,
                                                 short* __restrict__ outp) {
  const int p = blockIdx.y, c = p & 511;
  const int y = blockIdx.x * 2 + (threadIdx.x >> 7);
  const int x = threadIdx.x & 127;
  const short* ip = in + ((size_t)p << 14);
  float acc = bias[c];
#pragma unroll
  for (int ky = 0; ky < 3; ky++) {
    int yy = y + (ky - 1) * 2;
    if (yy < 0 || yy > 127) continue;
#pragma unroll
    for (int kx = 0; kx < 3; kx++) {
      int xx = x + (kx - 1) * 2;
      if (xx < 0 || xx > 127) continue;
      acc += bf2f(ip[yy * 128 + xx]) * w9[c * 9 + ky * 3 + kx];
    }
  }
  float center = bf2f(ip[y * 128 + x]);
  outp[((size_t)p << 14) + y * 128 + x] = f2bf(center + dscale[0] * acc);
}

// ---------------- fco GEMM + residual 2 -> out ----------------
__global__ __launch_bounds__(512) void fco_gemm(const short* __restrict__ h2,
                                                const float* __restrict__ w,
                                                const float* __restrict__ wb,
                                                const float* __restrict__ x1,
                                                const float* __restrict__ ls2,
                                                const float* __restrict__ st,
                                                float* __restrict__ out) {
  __shared__ short smem[128 * 40 + 192 * 40];
  short* A  = smem;
  short* Bl = smem + 128 * 40;
  const int m0 = blockIdx.x * 128;
  const int b = m0 >> 14;
  const int l0 = m0 & 16383;
  const int tid = threadIdx.x;
  const int wid = tid >> 6, lane = tid & 63;
  const int g = lane >> 4, h = lane & 15;
  const int wm = wid >> 2, wn = wid & 3;
  fx4 acc[4][3];
#pragma unroll
  for (int i = 0; i < 4; i++)
#pragma unroll
    for (int j = 0; j < 3; j++) acc[i][j] = fzero();

  for (int kt = 0; kt < 16; kt++) {
    const int k0 = kt * 32;
    {
      int cc = tid & 31, lg = tid >> 5;
      const short* src = h2 + (((size_t)(b * 512 + k0 + cc)) << 14) + l0 + lg * 8;
      bh8 v = *(const bh8*)src;
#pragma unroll
      for (int j = 0; j < 8; j++) A[(lg * 8 + j) * 40 + cc] = v[j];
    }
    for (int ch = tid; ch < 768; ch += 512) {
      int row = ch >> 2, part = ch & 3;
      *(bh8*)&Bl[row * 40 + part * 8] = pack8(w + (size_t)row * 512 + k0 + part * 8);
    }
    __syncthreads();
    bh8 af[4];
#pragma unroll
    for (int mi = 0; mi < 4; mi++)
      af[mi] = *(bh8*)&A[(wm * 64 + mi * 16 + h) * 40 + g * 8];
#pragma unroll
    for (int ni = 0; ni < 3; ni++) {
      bh8 bf = *(bh8*)&Bl[(wn * 48 + ni * 16 + h) * 40 + g * 8];
#pragma unroll
      for (int mi = 0; mi < 4; mi++) acc[mi][ni] = mfma16(af[mi], bf, acc[mi][ni]);
    }
    __syncthreads();
  }
  float s2 = st[b * 2 + 1];
#pragma unroll
  for (int mi = 0; mi < 4; mi++)
#pragma unroll
    for (int ni = 0; ni < 3; ni++)
#pragma unroll
      for (int r = 0; r < 4; r++) {
        int row = m0 + wm * 64 + mi * 16 + g * 4 + r;
        int col = wn * 48 + ni * 16 + h;
        size_t di = (size_t)row * 192 + col;
        out[di] = x1[di] + s2 * ls2[col] * (acc[mi][ni][r] + wb[col]);
      }
}

extern "C" void kernel_launch(void* const* d_in, const int* in_sizes, int n_in,
                              void* d_out, int out_size, void* d_ws, size_t ws_size,
                              hipStream_t stream) {
  const float* x      = (const float*)d_in[0];
  const float* qkv_w  = (const float*)d_in[1];
  const float* qkv_b  = (const float*)d_in[2];
  const float* proj_w = (const float*)d_in[3];
  const float* proj_b = (const float*)d_in[4];
  const float* rpb    = (const float*)d_in[5];
  const float* n1_w   = (const float*)d_in[6];
  const float* n1_b   = (const float*)d_in[7];
  const float* ls1    = (const float*)d_in[8];
  const float* n2_w   = (const float*)d_in[9];
  const float* n2_b   = (const float*)d_in[10];
  const float* ls2    = (const float*)d_in[11];
  const float* fcgv_w = (const float*)d_in[12];
  const float* fcgv_b = (const float*)d_in[13];
  const float* dw_w   = (const float*)d_in[14];
  const float* dw_b   = (const float*)d_in[15];
  const float* dwd_w  = (const float*)d_in[16];
  const float* dwd_b  = (const float*)d_in[17];
  const float* dil    = (const float*)d_in[18];
  const float* fco_w  = (const float*)d_in[19];
  const float* fco_b  = (const float*)d_in[20];
  float* out = (float*)d_out;
  char* ws = (char*)d_ws;

  // workspace layout (aliased). bt lives in the hp region (dead before fcgv writes hp).
  short* qb  = (short*)(ws + 0);          // 12.58 MB (dead after attn)
  short* kb  = (short*)(ws + 12582912);   // 12.58 MB (dead after attn)
  short* vb  = (short*)(ws + 25165824);   // 12.58 MB (dead after attn)
  short* ao  = (short*)(ws + 37748736);   // 12.58 MB (dead after proj)
  short* bt  = (short*)(ws + 50331648);   // 1.77 MB bias table (dead after attn)
  float* x1  = (float*)(ws + 0);          // 25.17 MB (over qb+kb)
  short* hp  = (short*)(ws + 25165824);   // 33.55 MB (over vb+ao+bt)
  short* y1  = (short*)(ws + 58720256);   // 33.55 MB
  short* h2  = (short*)(ws + 25165824);   // 33.55 MB (over hp, dead after conv1)
  float* part = (float*)(ws + 92274688);
  float* aff1 = (float*)(ws + 92278784);
  float* aff2 = (float*)(ws + 92281856);
  float* st1  = (float*)(ws + 92284928);
  float* st2  = (float*)(ws + 92284944);

  bias_gen<<<216, 256, 0, stream>>>(rpb, bt);
  iln_partial<<<512, 256, 0, stream>>>(x, part);
  iln_final<<<2, 256, 0, stream>>>(part, n1_w, n1_b, aff1, st1);
  qkv_gemm<<<dim3(256, 3), 512, 0, stream>>>(x, aff1, qkv_w, qkv_b, qb, kb, vb);
  attn_kernel<<<dim3(128, 6), 256, 0, stream>>>(qb, kb, vb, bt, ao);
  proj_gemm<<<dim3(256), 512, 0, stream>>>(ao, proj_w, proj_b, x, ls1, st1, x1);
  iln_partial<<<512, 256, 0, stream>>>(x1, part);
  iln_final<<<2, 256, 0, stream>>>(part, n2_w, n2_b, aff2, st2);
  fcgv_gemm<<<dim3(256, 4), 512, 0, stream>>>(x1, aff2, fcgv_w, fcgv_b, hp);
  dwconv_d1<<<dim3(64, 1024), 256, 0, stream>>>(hp, dw_w, dw_b, y1);
  dwconv_d2<<<dim3(64, 1024), 256, 0, stream>>>(y1, dwd_w, dwd_b, dil, h2);
  fco_gemm<<<dim3(256), 512, 0, stream>>>(h2, fco_w, fco_b, x1, ls2, st2, out);
}

// Round 3
// 228.049 us; speedup vs baseline: 2.1042x; 1.6913x over previous
//
#include <hip/hip_runtime.h>

#define DI __device__ __forceinline__

typedef __attribute__((ext_vector_type(8))) short bh8;
typedef __attribute__((ext_vector_type(4))) float fx4;
typedef __attribute__((ext_vector_type(16))) float fx16;

DI short f2bf(float f) {
  unsigned u = __builtin_bit_cast(unsigned, f);
  u += 0x7FFFu + ((u >> 16) & 1u);
  return (short)(u >> 16);
}
DI float bf2f(short s) {
  unsigned u = ((unsigned)(unsigned short)s) << 16;
  return __builtin_bit_cast(float, u);
}
DI fx4 mfma16(bh8 a, bh8 b, fx4 c) {
  return __builtin_amdgcn_mfma_f32_16x16x32_bf16(a, b, c, 0, 0, 0);
}
DI fx16 mfma32(bh8 a, bh8 b, fx16 c) {
  return __builtin_amdgcn_mfma_f32_32x32x16_bf16(a, b, c, 0, 0, 0);
}
DI fx4 fzero() { fx4 z = {0.f, 0.f, 0.f, 0.f}; return z; }

DI bh8 pack8(const float* src) {
  fx4 v0 = *(const fx4*)src;
  fx4 v1 = *(const fx4*)(src + 4);
  bh8 pk;
#pragma unroll
  for (int j = 0; j < 4; j++) { pk[j] = f2bf(v0[j]); pk[j + 4] = f2bf(v1[j]); }
  return pk;
}
DI bh8 pack8_aff(const float* src, const float* affc) {
  fx4 v0 = *(const fx4*)src;
  fx4 v1 = *(const fx4*)(src + 4);
  bh8 pk;
#pragma unroll
  for (int j = 0; j < 4; j++) {
    pk[j]     = f2bf(v0[j] * affc[2 * j]       + affc[2 * j + 1]);
    pk[j + 4] = f2bf(v1[j] * affc[2 * (j + 4)] + affc[2 * (j + 4) + 1]);
  }
  return pk;
}

// ---------------- holistic LN stats ----------------
__global__ __launch_bounds__(256) void iln_partial(const float* __restrict__ x,
                                                   float* __restrict__ part) {
  const int blk = blockIdx.x, tid = threadIdx.x;
  const fx4* p = (const fx4*)(x + (size_t)blk * 12288);
  float s = 0.f, s2 = 0.f;
#pragma unroll
  for (int i = 0; i < 12; i++) {
    fx4 v = p[i * 256 + tid];
    s  += v[0] + v[1] + v[2] + v[3];
    s2 += v[0] * v[0] + v[1] * v[1] + v[2] * v[2] + v[3] * v[3];
  }
  __shared__ float sm[512];
  sm[tid] = s; sm[256 + tid] = s2;
  __syncthreads();
  for (int st = 128; st > 0; st >>= 1) {
    if (tid < st) { sm[tid] += sm[tid + st]; sm[256 + tid] += sm[256 + tid + st]; }
    __syncthreads();
  }
  if (tid == 0) { part[blk * 2] = sm[0]; part[blk * 2 + 1] = sm[256]; }
}

__global__ __launch_bounds__(256) void iln_final(const float* __restrict__ part,
                                                 const float* __restrict__ w,
                                                 const float* __restrict__ bias,
                                                 float* __restrict__ aff,
                                                 float* __restrict__ st) {
  const int b = blockIdx.x, tid = threadIdx.x;
  __shared__ float sm[512];
  sm[tid]       = part[(b * 256 + tid) * 2];
  sm[256 + tid] = part[(b * 256 + tid) * 2 + 1];
  __syncthreads();
  for (int s = 128; s > 0; s >>= 1) {
    if (tid < s) { sm[tid] += sm[tid + s]; sm[256 + tid] += sm[256 + tid + s]; }
    __syncthreads();
  }
  const float invn = 1.f / 3145728.f;
  float mean = sm[0] * invn;
  float var  = sm[256] * invn - mean * mean;
  float scale = fminf(sqrtf(var + 1e-6f), 2.f);
  if (tid < 192) {
    float a = w[tid] / scale;
    aff[(b * 192 + tid) * 2]     = a;
    aff[(b * 192 + tid) * 2 + 1] = bias[tid] - mean * a;
  }
  if (tid == 0) { st[b * 2] = mean; st[b * 2 + 1] = scale; }
}

// ---------------- bias table gen: acc-register layout, bf16, pre-divided by SCALE ----------------
__global__ __launch_bounds__(256) void bias_gen(const float* __restrict__ rpb,
                                                short* __restrict__ bt) {
  int t = blockIdx.x * 256 + threadIdx.x;  // 55296 threads
  int lane = t & 63;
  int u = t >> 6;
  int qi = u & 1; u >>= 1;
  int ki = u & 1; u >>= 1;
  int kc = u % 9; u = u / 9;
  int w = u & 3, head = u >> 2;
  int c = lane & 31, hi = lane >> 5;
  int q = w * 64 + qi * 32 + c;
  int qterm = (q >> 4) * 39 + (q & 15);
  short o[16];
#pragma unroll
  for (int r = 0; r < 16; r++) {
    int k = kc * 64 + ki * 32 + (r & 3) + 8 * (r >> 2) + 4 * hi;
    int ky = (k * 2731) >> 16;                 // k/24 for k<600
    int kx = k - ky * 24;
    int idx = ky * 39 + kx + 600 - qterm;      // (ky-qy+15)*39 + (kx-qx+15)
    o[r] = f2bf(rpb[idx * 6 + head] * 5.656854249492381f);  // bias / SCALE
  }
  *(bh8*)(bt + (size_t)t * 16)     = *(bh8*)&o[0];
  *(bh8*)(bt + (size_t)t * 16 + 8) = *(bh8*)&o[8];
}

// ---------------- QKV GEMM: (32768x192) @ (576x192)^T -> q,k,v bf16 ----------------
__global__ __launch_bounds__(512) void qkv_gemm(const float* __restrict__ x,
                                                const float* __restrict__ aff,
                                                const float* __restrict__ w,
                                                const float* __restrict__ wb,
                                                short* __restrict__ qb,
                                                short* __restrict__ kb,
                                                short* __restrict__ vb) {
  __shared__ short smem[128 * 40 + 192 * 40];
  short* A  = smem;
  short* Bl = smem + 128 * 40;
  const int m0 = blockIdx.x * 128;
  const int n0 = blockIdx.y * 192;
  const int b = m0 >> 14;
  const float* affb = aff + b * 384;
  const int tid = threadIdx.x;
  const int wid = tid >> 6, lane = tid & 63;
  const int g = lane >> 4, h = lane & 15;
  const int wm = wid >> 2, wn = wid & 3;
  const int arow = tid >> 2, apart = tid & 3;
  fx4 acc[4][3];
#pragma unroll
  for (int i = 0; i < 4; i++)
#pragma unroll
    for (int j = 0; j < 3; j++) acc[i][j] = fzero();

  for (int kt = 0; kt < 6; kt++) {
    const int k0 = kt * 32;
    {
      const float* src = x + (size_t)(m0 + arow) * 192 + k0 + apart * 8;
      *(bh8*)&A[arow * 40 + apart * 8] = pack8_aff(src, affb + (k0 + apart * 8) * 2);
    }
    for (int ch = tid; ch < 768; ch += 512) {
      int row = ch >> 2, part = ch & 3;
      const float* src = w + (size_t)(n0 + row) * 192 + k0 + part * 8;
      *(bh8*)&Bl[row * 40 + part * 8] = pack8(src);
    }
    __syncthreads();
    bh8 af[4];
#pragma unroll
    for (int mi = 0; mi < 4; mi++)
      af[mi] = *(bh8*)&A[(wm * 64 + mi * 16 + h) * 40 + g * 8];
#pragma unroll
    for (int ni = 0; ni < 3; ni++) {
      bh8 bf = *(bh8*)&Bl[(wn * 48 + ni * 16 + h) * 40 + g * 8];
#pragma unroll
      for (int mi = 0; mi < 4; mi++) acc[mi][ni] = mfma16(af[mi], bf, acc[mi][ni]);
    }
    __syncthreads();
  }
  short* dst = (blockIdx.y == 0) ? qb : (blockIdx.y == 1 ? kb : vb);
#pragma unroll
  for (int mi = 0; mi < 4; mi++)
#pragma unroll
    for (int ni = 0; ni < 3; ni++)
#pragma unroll
      for (int r = 0; r < 4; r++) {
        int row = m0 + wm * 64 + mi * 16 + g * 4 + r;
        int col = wn * 48 + ni * 16 + h;
        dst[(size_t)row * 192 + col] = f2bf(acc[mi][ni][r] + wb[n0 + col]);
      }
}

// ---------------- attention: swapped-QK 32x32 MFMA, in-register P, no max ----------------
__global__ __launch_bounds__(256, 3) void attn_kernel(const short* __restrict__ qb,
                                                      const short* __restrict__ kb,
                                                      const short* __restrict__ vb,
                                                      const short* __restrict__ bt,
                                                      short* __restrict__ ao) {
  __shared__ short K_lds[64 * 40];
  __shared__ short Vt_lds[32 * 72];
  __shared__ float l_lds[256];
  const int tid = threadIdx.x;
  const int win = blockIdx.x, head = blockIdx.y;
  const int b = win >> 6, wy = (win >> 3) & 7, wx = win & 7;
  const int w = tid >> 6, lane = tid & 63, c = lane & 31, hi = lane >> 5;
  const float SCALE = 0.1767766952966369f;

  bh8 qf[2][2];
#pragma unroll
  for (int qi = 0; qi < 2; qi++) {
    int ql = w * 64 + qi * 32 + c;
    size_t gl = (size_t)(b * 16384 + (wy * 16 + (ql >> 4)) * 128 + wx * 16 + (ql & 15));
#pragma unroll
    for (int ds = 0; ds < 2; ds++)
      qf[qi][ds] = *(const bh8*)(qb + gl * 192 + head * 32 + ds * 16 + hi * 8);
  }
  float l_run[2] = {0.f, 0.f};
  fx16 out[2];
#pragma unroll
  for (int r = 0; r < 16; r++) { out[0][r] = 0.f; out[1][r] = 0.f; }

  const short* btw = bt + (size_t)(head * 4 + w) * 36864;

  const int kl_a = tid >> 2, part_a = tid & 3;
  const int kl_b = tid & 63, hg_b = tid >> 6;

  for (int kc = 0; kc < 9; kc++) {
    __syncthreads();
    {
      int key = kc * 64 + kl_a;
      int ky = key / 24, kx = key - ky * 24;
      int py = wy * 16 - 4 + ky, px = wx * 16 - 4 + kx;
      bh8 kv = {};
      if ((unsigned)py < 128u && (unsigned)px < 128u)
        kv = *(const bh8*)(kb + ((size_t)(b * 16384 + py * 128 + px)) * 192 + head * 32 + part_a * 8);
      *(bh8*)&K_lds[kl_a * 40 + part_a * 8] = kv;

      int key2 = kc * 64 + kl_b;
      int ky2 = key2 / 24, kx2 = key2 - ky2 * 24;
      int py2 = wy * 16 - 4 + ky2, px2 = wx * 16 - 4 + kx2;
      bh8 vv = {};
      if ((unsigned)py2 < 128u && (unsigned)px2 < 128u)
        vv = *(const bh8*)(vb + ((size_t)(b * 16384 + py2 * 128 + px2)) * 192 + head * 32 + hg_b * 8);
#pragma unroll
      for (int j = 0; j < 8; j++) Vt_lds[(hg_b * 8 + j) * 72 + kl_b] = vv[j];
    }
    __syncthreads();

#pragma unroll
    for (int ki = 0; ki < 2; ki++) {
      fx16 st[2];
#pragma unroll
      for (int qi = 0; qi < 2; qi++) {
        const short* bp = btw + (((kc * 2 + ki) * 2 + qi) * 64 + lane) * 16;
        int4 b0 = *(const int4*)bp;
        int4 b1 = *(const int4*)(bp + 8);
#pragma unroll
        for (int d2 = 0; d2 < 4; d2++) {
          unsigned u0 = ((const unsigned*)&b0)[d2];
          unsigned u1 = ((const unsigned*)&b1)[d2];
          st[qi][d2 * 2]     = __builtin_bit_cast(float, u0 << 16);
          st[qi][d2 * 2 + 1] = __builtin_bit_cast(float, u0 & 0xffff0000u);
          st[qi][8 + d2 * 2]     = __builtin_bit_cast(float, u1 << 16);
          st[qi][8 + d2 * 2 + 1] = __builtin_bit_cast(float, u1 & 0xffff0000u);
        }
      }
#pragma unroll
      for (int ds = 0; ds < 2; ds++) {
        bh8 kf = *(bh8*)&K_lds[(ki * 32 + c) * 40 + ds * 16 + hi * 8];
        st[0] = mfma32(kf, qf[0][ds], st[0]);
        st[1] = mfma32(kf, qf[1][ds], st[1]);
      }
#pragma unroll
      for (int qi = 0; qi < 2; qi++) {
        float s = 0.f;
#pragma unroll
        for (int r = 0; r < 16; r++) {
          float p = __expf(st[qi][r] * SCALE);
          st[qi][r] = p;
          s += p;
        }
        l_run[qi] += s;
      }
      int dwq[2][2][4];
#pragma unroll
      for (int qi = 0; qi < 2; qi++)
#pragma unroll
        for (int k1 = 0; k1 < 2; k1++)
#pragma unroll
          for (int p01 = 0; p01 < 2; p01++) {
            int rA = 2 * p01 + 8 * k1;
            int A, Bv;
            asm("v_cvt_pk_bf16_f32 %0, %1, %2" : "=v"(A)  : "v"(st[qi][rA]),     "v"(st[qi][rA + 1]));
            asm("v_cvt_pk_bf16_f32 %0, %1, %2" : "=v"(Bv) : "v"(st[qi][rA + 4]), "v"(st[qi][rA + 5]));
            int Ax = __shfl_xor(A, 32);
            int Bx = __shfl_xor(Bv, 32);
            dwq[qi][k1][p01]     = hi ? Bx : A;
            dwq[qi][k1][p01 + 2] = hi ? Bv : Ax;
          }
#pragma unroll
      for (int k1 = 0; k1 < 2; k1++) {
        bh8 bv2 = *(bh8*)&Vt_lds[c * 72 + (ki * 2 + k1) * 16 + hi * 8];
#pragma unroll
        for (int qi = 0; qi < 2; qi++) {
          int4 t4 = {dwq[qi][k1][0], dwq[qi][k1][1], dwq[qi][k1][2], dwq[qi][k1][3]};
          out[qi] = mfma32(__builtin_bit_cast(bh8, t4), bv2, out[qi]);
        }
      }
    }
  }
#pragma unroll
  for (int qi = 0; qi < 2; qi++) {
    float lp = l_run[qi] + __shfl_xor(l_run[qi], 32);
    l_lds[w * 64 + qi * 32 + c] = 1.f / lp;
  }
  __syncthreads();
#pragma unroll
  for (int qi = 0; qi < 2; qi++)
#pragma unroll
    for (int r = 0; r < 16; r++) {
      int row = (r & 3) + 8 * (r >> 2) + 4 * hi;
      float val = out[qi][r] * l_lds[w * 64 + qi * 32 + row];
      int ql = w * 64 + qi * 32 + row;
      ao[((size_t)(win * 256 + ql)) * 192 + head * 32 + c] = f2bf(val);
    }
}

// ---------------- proj GEMM + window reverse + residual 1 ----------------
__global__ __launch_bounds__(512) void proj_gemm(const short* __restrict__ ao,
                                                 const float* __restrict__ w,
                                                 const float* __restrict__ wb,
                                                 const float* __restrict__ x,
                                                 const float* __restrict__ ls1,
                                                 const float* __restrict__ st,
                                                 float* __restrict__ x1) {
  __shared__ short smem[128 * 40 + 192 * 40];
  short* A  = smem;
  short* Bl = smem + 128 * 40;
  const int m0 = blockIdx.x * 128;
  const int tid = threadIdx.x;
  const int wid = tid >> 6, lane = tid & 63;
  const int g = lane >> 4, h = lane & 15;
  const int wm = wid >> 2, wn = wid & 3;
  const int arow = tid >> 2, apart = tid & 3;
  fx4 acc[4][3];
#pragma unroll
  for (int i = 0; i < 4; i++)
#pragma unroll
    for (int j = 0; j < 3; j++) acc[i][j] = fzero();

  for (int kt = 0; kt < 6; kt++) {
    const int k0 = kt * 32;
    *(bh8*)&A[arow * 40 + apart * 8] =
        *(const bh8*)(ao + (size_t)(m0 + arow) * 192 + k0 + apart * 8);
    for (int ch = tid; ch < 768; ch += 512) {
      int row = ch >> 2, part = ch & 3;
      *(bh8*)&Bl[row * 40 + part * 8] = pack8(w + (size_t)row * 192 + k0 + part * 8);
    }
    __syncthreads();
    bh8 af[4];
#pragma unroll
    for (int mi = 0; mi < 4; mi++)
      af[mi] = *(bh8*)&A[(wm * 64 + mi * 16 + h) * 40 + g * 8];
#pragma unroll
    for (int ni = 0; ni < 3; ni++) {
      bh8 bf = *(bh8*)&Bl[(wn * 48 + ni * 16 + h) * 40 + g * 8];
#pragma unroll
      for (int mi = 0; mi < 4; mi++) acc[mi][ni] = mfma16(af[mi], bf, acc[mi][ni]);
    }
    __syncthreads();
  }
#pragma unroll
  for (int mi = 0; mi < 4; mi++)
#pragma unroll
    for (int ni = 0; ni < 3; ni++)
#pragma unroll
      for (int r = 0; r < 4; r++) {
        int grow = m0 + wm * 64 + mi * 16 + g * 4 + r;
        int win = grow >> 8, q = grow & 255;
        int bb = win >> 6, wy = (win >> 3) & 7, wxx = win & 7;
        int l = (wy * 16 + (q >> 4)) * 128 + wxx * 16 + (q & 15);
        int col = wn * 48 + ni * 16 + h;
        size_t di = ((size_t)(bb * 16384 + l)) * 192 + col;
        float s1 = st[bb * 2 + 1];
        x1[di] = x[di] + s1 * ls1[col] * (acc[mi][ni][r] + wb[col]);
      }
}

// ---------------- fcgv GEMM + SiLU gate -> planar h ----------------
__global__ __launch_bounds__(512) void fcgv_gemm(const float* __restrict__ x1,
                                                 const float* __restrict__ aff,
                                                 const float* __restrict__ w,
                                                 const float* __restrict__ wb,
                                                 short* __restrict__ hp) {
  __shared__ short smem[128 * 40 + 256 * 40];
  short* A  = smem;
  short* Bl = smem + 128 * 40;
  const int m0 = blockIdx.x * 128;
  const int n0 = blockIdx.y * 128;
  const int b = m0 >> 14;
  const int l0 = m0 & 16383;
  const float* affb = aff + b * 384;
  const int tid = threadIdx.x;
  const int wid = tid >> 6, lane = tid & 63;
  const int g = lane >> 4, h = lane & 15;
  const int wm = wid >> 2, wn = wid & 3;
  const int arow = tid >> 2, apart = tid & 3;
  fx4 accg[4][2], accv[4][2];
#pragma unroll
  for (int i = 0; i < 4; i++)
#pragma unroll
    for (int j = 0; j < 2; j++) { accg[i][j] = fzero(); accv[i][j] = fzero(); }

  for (int kt = 0; kt < 6; kt++) {
    const int k0 = kt * 32;
    {
      const float* src = x1 + (size_t)(m0 + arow) * 192 + k0 + apart * 8;
      *(bh8*)&A[arow * 40 + apart * 8] = pack8_aff(src, affb + (k0 + apart * 8) * 2);
    }
    for (int ch = tid; ch < 1024; ch += 512) {
      int row = ch >> 2, part = ch & 3;
      int wrow = (row < 128) ? (n0 + row) : (512 + n0 + row - 128);
      *(bh8*)&Bl[row * 40 + part * 8] = pack8(w + (size_t)wrow * 192 + k0 + part * 8);
    }
    __syncthreads();
    bh8 af[4];
#pragma unroll
    for (int mi = 0; mi < 4; mi++)
      af[mi] = *(bh8*)&A[(wm * 64 + mi * 16 + h) * 40 + g * 8];
#pragma unroll
    for (int ni = 0; ni < 2; ni++) {
      bh8 bg = *(bh8*)&Bl[(wn * 32 + ni * 16 + h) * 40 + g * 8];
      bh8 bv = *(bh8*)&Bl[(128 + wn * 32 + ni * 16 + h) * 40 + g * 8];
#pragma unroll
      for (int mi = 0; mi < 4; mi++) {
        accg[mi][ni] = mfma16(af[mi], bg, accg[mi][ni]);
        accv[mi][ni] = mfma16(af[mi], bv, accv[mi][ni]);
      }
    }
    __syncthreads();
  }
  short hs[4][2][4];
#pragma unroll
  for (int mi = 0; mi < 4; mi++)
#pragma unroll
    for (int ni = 0; ni < 2; ni++)
#pragma unroll
      for (int r = 0; r < 4; r++) {
        int colg = n0 + wn * 32 + ni * 16 + h;
        float gv = accg[mi][ni][r] + wb[colg];
        float vv = accv[mi][ni][r] + wb[512 + colg];
        float hval = gv / (1.f + __expf(-gv)) * vv;
        hs[mi][ni][r] = f2bf(hval);
      }
  short* T = smem;
  for (int p = 0; p < 2; p++) {
    if ((wn >> 1) == p) {
#pragma unroll
      for (int mi = 0; mi < 4; mi++)
#pragma unroll
        for (int ni = 0; ni < 2; ni++)
#pragma unroll
          for (int r = 0; r < 4; r++) {
            int cc = (wn & 1) * 32 + ni * 16 + h;
            int rl = wm * 64 + mi * 16 + g * 4 + r;
            T[cc * 136 + rl] = hs[mi][ni][r];
          }
    }
    __syncthreads();
    for (int ch = tid; ch < 1024; ch += 512) {
      int cc = ch >> 4, lg = ch & 15;
      bh8 v = *(bh8*)&T[cc * 136 + lg * 8];
      *(bh8*)(hp + (((size_t)(b * 512 + n0 + p * 64 + cc)) << 14) + l0 + lg * 8) = v;
    }
    __syncthreads();
  }
}

// ---------------- fused depthwise convs (one plane per block, LDS-staged) ----------------
// LDS row stride 136 shorts (272B): row y starts at dword 68y -> bank base 4y mod 32,
// giving the uniform 8-dwords/bank pattern for wave-wide ds_read_b128 (conflict-free).
__global__ __launch_bounds__(256, 2) void dw_fused(const short* __restrict__ in,
                                                   const float* __restrict__ w1,
                                                   const float* __restrict__ b1,
                                                   const float* __restrict__ w2,
                                                   const float* __restrict__ b2,
                                                   const float* __restrict__ dsc,
                                                   short* __restrict__ outp) {
  __shared__ short P[136 * 128];
  __shared__ short D[136 * 128];
  const int p = blockIdx.x, c = p & 511;
  const int tid = threadIdx.x;
  // stage plane: global slot gs -> row gs>>4, slot gs&15
#pragma unroll
  for (int i = 0; i < 8; i++) {
    int gs = i * 256 + tid;
    int yy = gs >> 4, sl = gs & 15;
    bh8 v = *(const bh8*)(in + ((size_t)p << 14) + gs * 8);
    *(bh8*)&P[yy * 136 + sl * 8] = v;
  }
  float k1[9], k2[9];
#pragma unroll
  for (int j = 0; j < 9; j++) { k1[j] = w1[c * 9 + j]; k2[j] = w2[c * 9 + j]; }
  const float bias1 = b1[c], bias2 = b2[c], ds = dsc[0];
  const int y = tid >> 1, hf = tid & 1;
  __syncthreads();

  // conv1 (dil 1) -> D
#pragma unroll
  for (int g = 0; g < 8; g++) {
    const int x0 = hf * 64 + g * 8;
    float acc[8];
#pragma unroll
    for (int i = 0; i < 8; i++) acc[i] = bias1;
#pragma unroll
    for (int ky = 0; ky < 3; ky++) {
      int yy = y + ky - 1;
      if ((unsigned)yy < 128u) {
        const short* row = &P[yy * 136];
        float f[10];
        bh8 v = *(const bh8*)&row[x0];
#pragma unroll
        for (int j = 0; j < 8; j++) f[j + 1] = bf2f(v[j]);
        f[0] = (x0 == 0) ? 0.f : bf2f(row[x0 - 1]);
        f[9] = (x0 == 120) ? 0.f : bf2f(row[x0 + 8]);
        float w0 = k1[ky * 3], wA = k1[ky * 3 + 1], wB = k1[ky * 3 + 2];
#pragma unroll
        for (int i = 0; i < 8; i++) acc[i] += f[i] * w0 + f[i + 1] * wA + f[i + 2] * wB;
      }
    }
    bh8 pk;
#pragma unroll
    for (int i = 0; i < 8; i++) pk[i] = f2bf(acc[i]);
    *(bh8*)&D[y * 136 + x0] = pk;
  }
  __syncthreads();

  // conv2 (dil 2) on D; out = D_center + ds * (bias2 + conv2)
#pragma unroll
  for (int g = 0; g < 8; g++) {
    const int x0 = hf * 64 + g * 8;
    float acc[8], center[8];
#pragma unroll
    for (int i = 0; i < 8; i++) acc[i] = bias2;
#pragma unroll
    for (int ky = 0; ky < 3; ky++) {
      int yy = y + (ky - 1) * 2;
      if ((unsigned)yy < 128u) {
        const short* row = &D[yy * 136];
        float f[12];
        bh8 v = *(const bh8*)&row[x0];
#pragma unroll
        for (int j = 0; j < 8; j++) f[j + 2] = bf2f(v[j]);
        if (x0 == 0) { f[0] = 0.f; f[1] = 0.f; }
        else {
          unsigned lp = *(const unsigned*)&row[x0 - 2];
          f[0] = __builtin_bit_cast(float, lp << 16);
          f[1] = __builtin_bit_cast(float, lp & 0xffff0000u);
        }
        if (x0 == 120) { f[10] = 0.f; f[11] = 0.f; }
        else {
          unsigned rp = *(const unsigned*)&row[x0 + 8];
          f[10] = __builtin_bit_cast(float, rp << 16);
          f[11] = __builtin_bit_cast(float, rp & 0xffff0000u);
        }
        float w0 = k2[ky * 3], wA = k2[ky * 3 + 1], wB = k2[ky * 3 + 2];
#pragma unroll
        for (int i = 0; i < 8; i++) acc[i] += f[i] * w0 + f[i + 2] * wA + f[i + 4] * wB;
        if (ky == 1) {
#pragma unroll
          for (int i = 0; i < 8; i++) center[i] = f[i + 2];
        }
      }
    }
    bh8 pk;
#pragma unroll
    for (int i = 0; i < 8; i++) pk[i] = f2bf(center[i] + ds * acc[i]);
    *(bh8*)(outp + ((size_t)p << 14) + y * 128 + x0) = pk;
  }
}

// ---------------- fco GEMM + residual 2 -> out ----------------
__global__ __launch_bounds__(512) void fco_gemm(const short* __restrict__ h2,
                                                const float* __restrict__ w,
                                                const float* __restrict__ wb,
                                                const float* __restrict__ x1,
                                                const float* __restrict__ ls2,
                                                const float* __restrict__ st,
                                                float* __restrict__ out) {
  __shared__ short smem[128 * 40 + 192 * 40];
  short* A  = smem;
  short* Bl = smem + 128 * 40;
  const int m0 = blockIdx.x * 128;
  const int b = m0 >> 14;
  const int l0 = m0 & 16383;
  const int tid = threadIdx.x;
  const int wid = tid >> 6, lane = tid & 63;
  const int g = lane >> 4, h = lane & 15;
  const int wm = wid >> 2, wn = wid & 3;
  fx4 acc[4][3];
#pragma unroll
  for (int i = 0; i < 4; i++)
#pragma unroll
    for (int j = 0; j < 3; j++) acc[i][j] = fzero();

  for (int kt = 0; kt < 16; kt++) {
    const int k0 = kt * 32;
    {
      int cc = tid & 31, lg = tid >> 5;
      const short* src = h2 + (((size_t)(b * 512 + k0 + cc)) << 14) + l0 + lg * 8;
      bh8 v = *(const bh8*)src;
#pragma unroll
      for (int j = 0; j < 8; j++) A[(lg * 8 + j) * 40 + cc] = v[j];
    }
    for (int ch = tid; ch < 768; ch += 512) {
      int row = ch >> 2, part = ch & 3;
      *(bh8*)&Bl[row * 40 + part * 8] = pack8(w + (size_t)row * 512 + k0 + part * 8);
    }
    __syncthreads();
    bh8 af[4];
#pragma unroll
    for (int mi = 0; mi < 4; mi++)
      af[mi] = *(bh8*)&A[(wm * 64 + mi * 16 + h) * 40 + g * 8];
#pragma unroll
    for (int ni = 0; ni < 3; ni++) {
      bh8 bf = *(bh8*)&Bl[(wn * 48 + ni * 16 + h) * 40 + g * 8];
#pragma unroll
      for (int mi = 0; mi < 4; mi++) acc[mi][ni] = mfma16(af[mi], bf, acc[mi][ni]);
    }
    __syncthreads();
  }
  float s2 = st[b * 2 + 1];
#pragma unroll
  for (int mi = 0; mi < 4; mi++)
#pragma unroll
    for (int ni = 0; ni < 3; ni++)
#pragma unroll
      for (int r = 0; r < 4; r++) {
        int row = m0 + wm * 64 + mi * 16 + g * 4 + r;
        int col = wn * 48 + ni * 16 + h;
        size_t di = (size_t)row * 192 + col;
        out[di] = x1[di] + s2 * ls2[col] * (acc[mi][ni][r] + wb[col]);
      }
}

extern "C" void kernel_launch(void* const* d_in, const int* in_sizes, int n_in,
                              void* d_out, int out_size, void* d_ws, size_t ws_size,
                              hipStream_t stream) {
  const float* x      = (const float*)d_in[0];
  const float* qkv_w  = (const float*)d_in[1];
  const float* qkv_b  = (const float*)d_in[2];
  const float* proj_w = (const float*)d_in[3];
  const float* proj_b = (const float*)d_in[4];
  const float* rpb    = (const float*)d_in[5];
  const float* n1_w   = (const float*)d_in[6];
  const float* n1_b   = (const float*)d_in[7];
  const float* ls1    = (const float*)d_in[8];
  const float* n2_w   = (const float*)d_in[9];
  const float* n2_b   = (const float*)d_in[10];
  const float* ls2    = (const float*)d_in[11];
  const float* fcgv_w = (const float*)d_in[12];
  const float* fcgv_b = (const float*)d_in[13];
  const float* dw_w   = (const float*)d_in[14];
  const float* dw_b   = (const float*)d_in[15];
  const float* dwd_w  = (const float*)d_in[16];
  const float* dwd_b  = (const float*)d_in[17];
  const float* dil    = (const float*)d_in[18];
  const float* fco_w  = (const float*)d_in[19];
  const float* fco_b  = (const float*)d_in[20];
  float* out = (float*)d_out;
  char* ws = (char*)d_ws;

  short* qb  = (short*)(ws + 0);          // 12.58 MB (dead after attn)
  short* kb  = (short*)(ws + 12582912);   // 12.58 MB (dead after attn)
  short* vb  = (short*)(ws + 25165824);   // 12.58 MB (dead after attn)
  short* ao  = (short*)(ws + 37748736);   // 12.58 MB (dead after proj)
  short* bt  = (short*)(ws + 50331648);   // 1.77 MB bias table (dead after attn)
  float* x1  = (float*)(ws + 0);          // 25.17 MB (over qb+kb)
  short* hp  = (short*)(ws + 25165824);   // 33.55 MB (over vb+ao+bt)
  short* h2  = (short*)(ws + 58720256);   // 33.55 MB
  float* part = (float*)(ws + 92274688);
  float* aff1 = (float*)(ws + 92278784);
  float* aff2 = (float*)(ws + 92281856);
  float* st1  = (float*)(ws + 92284928);
  float* st2  = (float*)(ws + 92284944);

  bias_gen<<<216, 256, 0, stream>>>(rpb, bt);
  iln_partial<<<512, 256, 0, stream>>>(x, part);
  iln_final<<<2, 256, 0, stream>>>(part, n1_w, n1_b, aff1, st1);
  qkv_gemm<<<dim3(256, 3), 512, 0, stream>>>(x, aff1, qkv_w, qkv_b, qb, kb, vb);
  attn_kernel<<<dim3(128, 6), 256, 0, stream>>>(qb, kb, vb, bt, ao);
  proj_gemm<<<dim3(256), 512, 0, stream>>>(ao, proj_w, proj_b, x, ls1, st1, x1);
  iln_partial<<<512, 256, 0, stream>>>(x1, part);
  iln_final<<<2, 256, 0, stream>>>(part, n2_w, n2_b, aff2, st2);
  fcgv_gemm<<<dim3(256, 4), 512, 0, stream>>>(x1, aff2, fcgv_w, fcgv_b, hp);
  dw_fused<<<1024, 256, 0, stream>>>(hp, dw_w, dw_b, dwd_w, dwd_b, dil, h2);
  fco_gemm<<<dim3(256), 512, 0, stream>>>(h2, fco_w, fco_b, x1, ls2, st2, out);
}

// Round 4
// 189.896 us; speedup vs baseline: 2.5270x; 1.2009x over previous
//
#include <hip/hip_runtime.h>

#define DI __device__ __forceinline__

typedef __attribute__((ext_vector_type(8))) short bh8;
typedef __attribute__((ext_vector_type(4))) float fx4;
typedef __attribute__((ext_vector_type(16))) float fx16;

DI short f2bf(float f) {
  unsigned u = __builtin_bit_cast(unsigned, f);
  u += 0x7FFFu + ((u >> 16) & 1u);
  return (short)(u >> 16);
}
DI float bf2f(short s) {
  unsigned u = ((unsigned)(unsigned short)s) << 16;
  return __builtin_bit_cast(float, u);
}
DI fx4 mfma16(bh8 a, bh8 b, fx4 c) {
  return __builtin_amdgcn_mfma_f32_16x16x32_bf16(a, b, c, 0, 0, 0);
}
DI fx16 mfma32(bh8 a, bh8 b, fx16 c) {
  return __builtin_amdgcn_mfma_f32_32x32x16_bf16(a, b, c, 0, 0, 0);
}
DI fx4 fzero() { fx4 z = {0.f, 0.f, 0.f, 0.f}; return z; }

DI bh8 pack8(const float* src) {
  fx4 v0 = *(const fx4*)src;
  fx4 v1 = *(const fx4*)(src + 4);
  bh8 pk;
#pragma unroll
  for (int j = 0; j < 4; j++) { pk[j] = f2bf(v0[j]); pk[j + 4] = f2bf(v1[j]); }
  return pk;
}
DI bh8 pack8_aff(const float* src, const float* affc) {
  fx4 v0 = *(const fx4*)src;
  fx4 v1 = *(const fx4*)(src + 4);
  bh8 pk;
#pragma unroll
  for (int j = 0; j < 4; j++) {
    pk[j]     = f2bf(v0[j] * affc[2 * j]       + affc[2 * j + 1]);
    pk[j + 4] = f2bf(v1[j] * affc[2 * (j + 4)] + affc[2 * (j + 4) + 1]);
  }
  return pk;
}

// ---------------- holistic LN stats (pass over x only) ----------------
__global__ __launch_bounds__(256) void iln_partial(const float* __restrict__ x,
                                                   float* __restrict__ part) {
  const int blk = blockIdx.x, tid = threadIdx.x;
  const fx4* p = (const fx4*)(x + (size_t)blk * 12288);
  float s = 0.f, s2 = 0.f;
#pragma unroll
  for (int i = 0; i < 12; i++) {
    fx4 v = p[i * 256 + tid];
    s  += v[0] + v[1] + v[2] + v[3];
    s2 += v[0] * v[0] + v[1] * v[1] + v[2] * v[2] + v[3] * v[3];
  }
  __shared__ float sm[512];
  sm[tid] = s; sm[256 + tid] = s2;
  __syncthreads();
  for (int st = 128; st > 0; st >>= 1) {
    if (tid < st) { sm[tid] += sm[tid + st]; sm[256 + tid] += sm[256 + tid + st]; }
    __syncthreads();
  }
  if (tid == 0) { part[blk * 2] = sm[0]; part[blk * 2 + 1] = sm[256]; }
}

// reads 256 partials per batch; works for iln1 (part) and iln2 (part2 from proj)
__global__ __launch_bounds__(256) void iln_final(const float* __restrict__ part,
                                                 const float* __restrict__ w,
                                                 const float* __restrict__ bias,
                                                 float* __restrict__ aff,
                                                 float* __restrict__ st) {
  const int b = blockIdx.x, tid = threadIdx.x;
  __shared__ float sm[512];
  sm[tid]       = part[(b * 256 + tid) * 2];
  sm[256 + tid] = part[(b * 256 + tid) * 2 + 1];
  __syncthreads();
  for (int s = 128; s > 0; s >>= 1) {
    if (tid < s) { sm[tid] += sm[tid + s]; sm[256 + tid] += sm[256 + tid + s]; }
    __syncthreads();
  }
  const float invn = 1.f / 3145728.f;
  float mean = sm[0] * invn;
  float var  = sm[256] * invn - mean * mean;
  float scale = fminf(sqrtf(var + 1e-6f), 2.f);
  if (tid < 192) {
    float a = w[tid] / scale;
    aff[(b * 192 + tid) * 2]     = a;
    aff[(b * 192 + tid) * 2 + 1] = bias[tid] - mean * a;
  }
  if (tid == 0) { st[b * 2] = mean; st[b * 2 + 1] = scale; }
}

// ---------------- weight convert: [qkv_w | proj_w | fcgv_w | fco_w] -> bf16 ----------------
__global__ __launch_bounds__(256) void cvt_w(const float* __restrict__ qkv_w,
                                             const float* __restrict__ proj_w,
                                             const float* __restrict__ fcgv_w,
                                             const float* __restrict__ fco_w,
                                             short* __restrict__ wbuf) {
  int t = blockIdx.x * 256 + threadIdx.x;  // 55296 threads
  int off = t * 8;
  const float* src;
  if (off < 110592)       src = qkv_w + off;
  else if (off < 147456)  src = proj_w + (off - 110592);
  else if (off < 344064)  src = fcgv_w + (off - 147456);
  else                    src = fco_w + (off - 344064);
  *(bh8*)(wbuf + off) = pack8(src);
}

// ---------------- activation convert with affine: fp32 -> bf16 ----------------
__global__ __launch_bounds__(256) void cvt_aff(const float* __restrict__ src,
                                               const float* __restrict__ aff,
                                               short* __restrict__ dst) {
  int t = blockIdx.x * 256 + threadIdx.x;  // 786432 threads
  int row = t / 24;
  int c0 = (t - row * 24) * 8;
  const float* affp = aff + (row >> 14) * 384 + c0 * 2;
  *(bh8*)(dst + (size_t)t * 8) = pack8_aff(src + (size_t)row * 192 + c0, affp);
}

// ---------------- bias table gen: acc-register layout, bf16, pre-divided by SCALE ----------------
__global__ __launch_bounds__(256) void bias_gen(const float* __restrict__ rpb,
                                                short* __restrict__ bt) {
  int t = blockIdx.x * 256 + threadIdx.x;  // 55296 threads
  int lane = t & 63;
  int u = t >> 6;
  int qi = u & 1; u >>= 1;
  int ki = u & 1; u >>= 1;
  int kc = u % 9; u = u / 9;
  int w = u & 3, head = u >> 2;
  int c = lane & 31, hi = lane >> 5;
  int q = w * 64 + qi * 32 + c;
  int qterm = (q >> 4) * 39 + (q & 15);
  short o[16];
#pragma unroll
  for (int r = 0; r < 16; r++) {
    int k = kc * 64 + ki * 32 + (r & 3) + 8 * (r >> 2) + 4 * hi;
    int ky = (k * 2731) >> 16;
    int kx = k - ky * 24;
    int idx = ky * 39 + kx + 600 - qterm;
    o[r] = f2bf(rpb[idx * 6 + head] * 5.656854249492381f);
  }
  *(bh8*)(bt + (size_t)t * 16)     = *(bh8*)&o[0];
  *(bh8*)(bt + (size_t)t * 16 + 8) = *(bh8*)&o[8];
}

// ---------------- QKV GEMM (bf16 operands): tile 128x96, grid (256,6) ----------------
__global__ __launch_bounds__(256) void gemm_qkv(const short* __restrict__ xn,
                                                const short* __restrict__ wq,
                                                const float* __restrict__ wb,
                                                short* __restrict__ qb,
                                                short* __restrict__ kb,
                                                short* __restrict__ vb) {
  __shared__ short As[128 * 40];
  __shared__ short Bs[96 * 40];
  const int m0 = blockIdx.x * 128, by = blockIdx.y, n0 = by * 96;
  const int tid = threadIdx.x, wid = tid >> 6, lane = tid & 63;
  const int g = lane >> 4, h = lane & 15;
  const int wm = wid >> 1, wn = wid & 1;
  fx4 acc[4][3];
#pragma unroll
  for (int i = 0; i < 4; i++)
#pragma unroll
    for (int j = 0; j < 3; j++) acc[i][j] = fzero();

  for (int kt = 0; kt < 6; kt++) {
    const int k0 = kt * 32;
#pragma unroll
    for (int i = 0; i < 2; i++) {
      int ch = tid + i * 256;
      int row = ch >> 2, sl = ch & 3;
      *(bh8*)&As[row * 40 + sl * 8] = *(const bh8*)(xn + (size_t)(m0 + row) * 192 + k0 + sl * 8);
    }
    {
      int row = tid >> 2, sl = tid & 3;
      *(bh8*)&Bs[row * 40 + sl * 8] = *(const bh8*)(wq + (size_t)(n0 + row) * 192 + k0 + sl * 8);
      int ch = tid + 256;
      if (ch < 384) {
        row = ch >> 2; sl = ch & 3;
        *(bh8*)&Bs[row * 40 + sl * 8] = *(const bh8*)(wq + (size_t)(n0 + row) * 192 + k0 + sl * 8);
      }
    }
    __syncthreads();
    bh8 af[4];
#pragma unroll
    for (int mi = 0; mi < 4; mi++)
      af[mi] = *(bh8*)&As[(wm * 64 + mi * 16 + h) * 40 + g * 8];
#pragma unroll
    for (int ni = 0; ni < 3; ni++) {
      bh8 bf = *(bh8*)&Bs[(wn * 48 + ni * 16 + h) * 40 + g * 8];
#pragma unroll
      for (int mi = 0; mi < 4; mi++) acc[mi][ni] = mfma16(af[mi], bf, acc[mi][ni]);
    }
    __syncthreads();
  }
  const int seg = by >> 1;
  short* dst = (seg == 0) ? qb : (seg == 1 ? kb : vb);
  const int colbase = (by & 1) * 96;
#pragma unroll
  for (int mi = 0; mi < 4; mi++)
#pragma unroll
    for (int ni = 0; ni < 3; ni++)
#pragma unroll
      for (int r = 0; r < 4; r++) {
        int row = m0 + wm * 64 + mi * 16 + g * 4 + r;
        int col = colbase + wn * 48 + ni * 16 + h;
        dst[(size_t)row * 192 + col] = f2bf(acc[mi][ni][r] + wb[seg * 192 + col]);
      }
}

// ---------------- attention: swapped-QK 32x32 MFMA, in-register P, no max ----------------
__global__ __launch_bounds__(256, 3) void attn_kernel(const short* __restrict__ qb,
                                                      const short* __restrict__ kb,
                                                      const short* __restrict__ vb,
                                                      const short* __restrict__ bt,
                                                      short* __restrict__ ao) {
  __shared__ short K_lds[64 * 40];
  __shared__ short Vt_lds[32 * 72];
  __shared__ float l_lds[256];
  const int tid = threadIdx.x;
  const int win = blockIdx.x, head = blockIdx.y;
  const int b = win >> 6, wy = (win >> 3) & 7, wx = win & 7;
  const int w = tid >> 6, lane = tid & 63, c = lane & 31, hi = lane >> 5;
  const float SCALE = 0.1767766952966369f;

  bh8 qf[2][2];
#pragma unroll
  for (int qi = 0; qi < 2; qi++) {
    int ql = w * 64 + qi * 32 + c;
    size_t gl = (size_t)(b * 16384 + (wy * 16 + (ql >> 4)) * 128 + wx * 16 + (ql & 15));
#pragma unroll
    for (int ds = 0; ds < 2; ds++)
      qf[qi][ds] = *(const bh8*)(qb + gl * 192 + head * 32 + ds * 16 + hi * 8);
  }
  float l_run[2] = {0.f, 0.f};
  fx16 out[2];
#pragma unroll
  for (int r = 0; r < 16; r++) { out[0][r] = 0.f; out[1][r] = 0.f; }

  const short* btw = bt + (size_t)(head * 4 + w) * 36864;

  const int kl_a = tid >> 2, part_a = tid & 3;
  const int kl_b = tid & 63, hg_b = tid >> 6;

  for (int kc = 0; kc < 9; kc++) {
    __syncthreads();
    {
      int key = kc * 64 + kl_a;
      int ky = key / 24, kx = key - ky * 24;
      int py = wy * 16 - 4 + ky, px = wx * 16 - 4 + kx;
      bh8 kv = {};
      if ((unsigned)py < 128u && (unsigned)px < 128u)
        kv = *(const bh8*)(kb + ((size_t)(b * 16384 + py * 128 + px)) * 192 + head * 32 + part_a * 8);
      *(bh8*)&K_lds[kl_a * 40 + part_a * 8] = kv;

      int key2 = kc * 64 + kl_b;
      int ky2 = key2 / 24, kx2 = key2 - ky2 * 24;
      int py2 = wy * 16 - 4 + ky2, px2 = wx * 16 - 4 + kx2;
      bh8 vv = {};
      if ((unsigned)py2 < 128u && (unsigned)px2 < 128u)
        vv = *(const bh8*)(vb + ((size_t)(b * 16384 + py2 * 128 + px2)) * 192 + head * 32 + hg_b * 8);
#pragma unroll
      for (int j = 0; j < 8; j++) Vt_lds[(hg_b * 8 + j) * 72 + kl_b] = vv[j];
    }
    __syncthreads();

#pragma unroll
    for (int ki = 0; ki < 2; ki++) {
      fx16 st[2];
#pragma unroll
      for (int qi = 0; qi < 2; qi++) {
        const short* bp = btw + (((kc * 2 + ki) * 2 + qi) * 64 + lane) * 16;
        int4 b0 = *(const int4*)bp;
        int4 b1 = *(const int4*)(bp + 8);
#pragma unroll
        for (int d2 = 0; d2 < 4; d2++) {
          unsigned u0 = ((const unsigned*)&b0)[d2];
          unsigned u1 = ((const unsigned*)&b1)[d2];
          st[qi][d2 * 2]     = __builtin_bit_cast(float, u0 << 16);
          st[qi][d2 * 2 + 1] = __builtin_bit_cast(float, u0 & 0xffff0000u);
          st[qi][8 + d2 * 2]     = __builtin_bit_cast(float, u1 << 16);
          st[qi][8 + d2 * 2 + 1] = __builtin_bit_cast(float, u1 & 0xffff0000u);
        }
      }
#pragma unroll
      for (int ds = 0; ds < 2; ds++) {
        bh8 kf = *(bh8*)&K_lds[(ki * 32 + c) * 40 + ds * 16 + hi * 8];
        st[0] = mfma32(kf, qf[0][ds], st[0]);
        st[1] = mfma32(kf, qf[1][ds], st[1]);
      }
#pragma unroll
      for (int qi = 0; qi < 2; qi++) {
        float s = 0.f;
#pragma unroll
        for (int r = 0; r < 16; r++) {
          float p = __expf(st[qi][r] * SCALE);
          st[qi][r] = p;
          s += p;
        }
        l_run[qi] += s;
      }
      int dwq[2][2][4];
#pragma unroll
      for (int qi = 0; qi < 2; qi++)
#pragma unroll
        for (int k1 = 0; k1 < 2; k1++)
#pragma unroll
          for (int p01 = 0; p01 < 2; p01++) {
            int rA = 2 * p01 + 8 * k1;
            int A, Bv;
            asm("v_cvt_pk_bf16_f32 %0, %1, %2" : "=v"(A)  : "v"(st[qi][rA]),     "v"(st[qi][rA + 1]));
            asm("v_cvt_pk_bf16_f32 %0, %1, %2" : "=v"(Bv) : "v"(st[qi][rA + 4]), "v"(st[qi][rA + 5]));
            int Ax = __shfl_xor(A, 32);
            int Bx = __shfl_xor(Bv, 32);
            dwq[qi][k1][p01]     = hi ? Bx : A;
            dwq[qi][k1][p01 + 2] = hi ? Bv : Ax;
          }
#pragma unroll
      for (int k1 = 0; k1 < 2; k1++) {
        bh8 bv2 = *(bh8*)&Vt_lds[c * 72 + (ki * 2 + k1) * 16 + hi * 8];
#pragma unroll
        for (int qi = 0; qi < 2; qi++) {
          int4 t4 = {dwq[qi][k1][0], dwq[qi][k1][1], dwq[qi][k1][2], dwq[qi][k1][3]};
          out[qi] = mfma32(__builtin_bit_cast(bh8, t4), bv2, out[qi]);
        }
      }
    }
  }
#pragma unroll
  for (int qi = 0; qi < 2; qi++) {
    float lp = l_run[qi] + __shfl_xor(l_run[qi], 32);
    l_lds[w * 64 + qi * 32 + c] = 1.f / lp;
  }
  __syncthreads();
#pragma unroll
  for (int qi = 0; qi < 2; qi++)
#pragma unroll
    for (int r = 0; r < 16; r++) {
      int row = (r & 3) + 8 * (r >> 2) + 4 * hi;
      float val = out[qi][r] * l_lds[w * 64 + qi * 32 + row];
      int ql = w * 64 + qi * 32 + row;
      ao[((size_t)(win * 256 + ql)) * 192 + head * 32 + c] = f2bf(val);
    }
}

// ---------------- proj GEMM + window reverse + residual 1 + iln2 partials ----------------
__global__ __launch_bounds__(256) void gemm_proj(const short* __restrict__ ao,
                                                 const short* __restrict__ wp,
                                                 const float* __restrict__ wb,
                                                 const float* __restrict__ x,
                                                 const float* __restrict__ ls1,
                                                 const float* __restrict__ st,
                                                 float* __restrict__ x1,
                                                 float* __restrict__ part2) {
  __shared__ short As[128 * 40];
  __shared__ short Bs[96 * 40];
  const int m0 = blockIdx.x * 128, by = blockIdx.y, n0 = by * 96;
  const int tid = threadIdx.x, wid = tid >> 6, lane = tid & 63;
  const int g = lane >> 4, h = lane & 15;
  const int wm = wid >> 1, wn = wid & 1;
  fx4 acc[4][3];
#pragma unroll
  for (int i = 0; i < 4; i++)
#pragma unroll
    for (int j = 0; j < 3; j++) acc[i][j] = fzero();

  for (int kt = 0; kt < 6; kt++) {
    const int k0 = kt * 32;
#pragma unroll
    for (int i = 0; i < 2; i++) {
      int ch = tid + i * 256;
      int row = ch >> 2, sl = ch & 3;
      *(bh8*)&As[row * 40 + sl * 8] = *(const bh8*)(ao + (size_t)(m0 + row) * 192 + k0 + sl * 8);
    }
    {
      int row = tid >> 2, sl = tid & 3;
      *(bh8*)&Bs[row * 40 + sl * 8] = *(const bh8*)(wp + (size_t)(n0 + row) * 192 + k0 + sl * 8);
      int ch = tid + 256;
      if (ch < 384) {
        row = ch >> 2; sl = ch & 3;
        *(bh8*)&Bs[row * 40 + sl * 8] = *(const bh8*)(wp + (size_t)(n0 + row) * 192 + k0 + sl * 8);
      }
    }
    __syncthreads();
    bh8 af[4];
#pragma unroll
    for (int mi = 0; mi < 4; mi++)
      af[mi] = *(bh8*)&As[(wm * 64 + mi * 16 + h) * 40 + g * 8];
#pragma unroll
    for (int ni = 0; ni < 3; ni++) {
      bh8 bf = *(bh8*)&Bs[(wn * 48 + ni * 16 + h) * 40 + g * 8];
#pragma unroll
      for (int mi = 0; mi < 4; mi++) acc[mi][ni] = mfma16(af[mi], bf, acc[mi][ni]);
    }
    __syncthreads();
  }
  float ps = 0.f, ps2 = 0.f;
#pragma unroll
  for (int mi = 0; mi < 4; mi++)
#pragma unroll
    for (int ni = 0; ni < 3; ni++)
#pragma unroll
      for (int r = 0; r < 4; r++) {
        int grow = m0 + wm * 64 + mi * 16 + g * 4 + r;
        int win = grow >> 8, q = grow & 255;
        int bb = win >> 6, wy = (win >> 3) & 7, wxx = win & 7;
        int l = (wy * 16 + (q >> 4)) * 128 + wxx * 16 + (q & 15);
        int col = n0 + wn * 48 + ni * 16 + h;
        size_t di = ((size_t)(bb * 16384 + l)) * 192 + col;
        float s1 = st[bb * 2 + 1];
        float val = x[di] + s1 * ls1[col] * (acc[mi][ni][r] + wb[col]);
        x1[di] = val;
        ps += val;
        ps2 += val * val;
      }
  float* red = (float*)As;
  red[tid] = ps; red[256 + tid] = ps2;
  __syncthreads();
  for (int s = 128; s > 0; s >>= 1) {
    if (tid < s) { red[tid] += red[tid + s]; red[256 + tid] += red[256 + tid + s]; }
    __syncthreads();
  }
  if (tid == 0) {
    int pi = blockIdx.x * 2 + by;
    part2[pi * 2] = red[0];
    part2[pi * 2 + 1] = red[256];
  }
}

// ---------------- fcgv GEMM (dual gate/val) + SiLU -> planar hp ----------------
__global__ __launch_bounds__(256) void gemm_fcgv(const short* __restrict__ x1n,
                                                 const short* __restrict__ wg,
                                                 const float* __restrict__ wb,
                                                 short* __restrict__ hp) {
  __shared__ short smem[128 * 40 + 128 * 40];
  short* As = smem;
  short* Bs = smem + 128 * 40;
  const int m0 = blockIdx.x * 128, n0 = blockIdx.y * 64;
  const int b = m0 >> 14, l0 = m0 & 16383;
  const int tid = threadIdx.x, wid = tid >> 6, lane = tid & 63;
  const int g = lane >> 4, h = lane & 15;
  const int wm = wid >> 1, wn = wid & 1;
  fx4 accg[4][2], accv[4][2];
#pragma unroll
  for (int i = 0; i < 4; i++)
#pragma unroll
    for (int j = 0; j < 2; j++) { accg[i][j] = fzero(); accv[i][j] = fzero(); }

  for (int kt = 0; kt < 6; kt++) {
    const int k0 = kt * 32;
#pragma unroll
    for (int i = 0; i < 2; i++) {
      int ch = tid + i * 256;
      int row = ch >> 2, sl = ch & 3;
      *(bh8*)&As[row * 40 + sl * 8] = *(const bh8*)(x1n + (size_t)(m0 + row) * 192 + k0 + sl * 8);
    }
#pragma unroll
    for (int i = 0; i < 2; i++) {
      int ch = tid + i * 256;
      int row = ch >> 2, sl = ch & 3;
      int wrow = (row < 64) ? (n0 + row) : (512 + n0 + row - 64);
      *(bh8*)&Bs[row * 40 + sl * 8] = *(const bh8*)(wg + (size_t)wrow * 192 + k0 + sl * 8);
    }
    __syncthreads();
    bh8 af[4];
#pragma unroll
    for (int mi = 0; mi < 4; mi++)
      af[mi] = *(bh8*)&As[(wm * 64 + mi * 16 + h) * 40 + g * 8];
#pragma unroll
    for (int ni = 0; ni < 2; ni++) {
      bh8 bg = *(bh8*)&Bs[(wn * 32 + ni * 16 + h) * 40 + g * 8];
      bh8 bv = *(bh8*)&Bs[(64 + wn * 32 + ni * 16 + h) * 40 + g * 8];
#pragma unroll
      for (int mi = 0; mi < 4; mi++) {
        accg[mi][ni] = mfma16(af[mi], bg, accg[mi][ni]);
        accv[mi][ni] = mfma16(af[mi], bv, accv[mi][ni]);
      }
    }
    __syncthreads();
  }
  short hs[4][2][4];
#pragma unroll
  for (int mi = 0; mi < 4; mi++)
#pragma unroll
    for (int ni = 0; ni < 2; ni++)
#pragma unroll
      for (int r = 0; r < 4; r++) {
        int colg = n0 + wn * 32 + ni * 16 + h;
        float gv = accg[mi][ni][r] + wb[colg];
        float vv = accv[mi][ni][r] + wb[512 + colg];
        hs[mi][ni][r] = f2bf(gv / (1.f + __expf(-gv)) * vv);
      }
  short* T = smem;  // 64 x 136 = 8704 shorts (17408 B <= 20480 B)
#pragma unroll
  for (int mi = 0; mi < 4; mi++)
#pragma unroll
    for (int ni = 0; ni < 2; ni++)
#pragma unroll
      for (int r = 0; r < 4; r++) {
        int cc = wn * 32 + ni * 16 + h;
        int rl = wm * 64 + mi * 16 + g * 4 + r;
        T[cc * 136 + rl] = hs[mi][ni][r];
      }
  __syncthreads();
#pragma unroll
  for (int i = 0; i < 4; i++) {
    int ch = tid + i * 256;
    int cc = ch >> 4, lg = ch & 15;
    bh8 v = *(bh8*)&T[cc * 136 + lg * 8];
    *(bh8*)(hp + (((size_t)(b * 512 + n0 + cc)) << 14) + l0 + lg * 8) = v;
  }
}

// ---------------- fused depthwise convs (in-place safe: plane-local) ----------------
__global__ __launch_bounds__(256, 2) void dw_fused(const short* __restrict__ in,
                                                   const float* __restrict__ w1,
                                                   const float* __restrict__ b1,
                                                   const float* __restrict__ w2,
                                                   const float* __restrict__ b2,
                                                   const float* __restrict__ dsc,
                                                   short* __restrict__ outp) {
  __shared__ short P[136 * 128];
  __shared__ short D[136 * 128];
  const int p = blockIdx.x, c = p & 511;
  const int tid = threadIdx.x;
#pragma unroll
  for (int i = 0; i < 8; i++) {
    int gs = i * 256 + tid;
    int yy = gs >> 4, sl = gs & 15;
    bh8 v = *(const bh8*)(in + ((size_t)p << 14) + gs * 8);
    *(bh8*)&P[yy * 136 + sl * 8] = v;
  }
  float k1[9], k2[9];
#pragma unroll
  for (int j = 0; j < 9; j++) { k1[j] = w1[c * 9 + j]; k2[j] = w2[c * 9 + j]; }
  const float bias1 = b1[c], bias2 = b2[c], ds = dsc[0];
  const int y = tid >> 1, hf = tid & 1;
  __syncthreads();

#pragma unroll
  for (int g = 0; g < 8; g++) {
    const int x0 = hf * 64 + g * 8;
    float acc[8];
#pragma unroll
    for (int i = 0; i < 8; i++) acc[i] = bias1;
#pragma unroll
    for (int ky = 0; ky < 3; ky++) {
      int yy = y + ky - 1;
      if ((unsigned)yy < 128u) {
        const short* row = &P[yy * 136];
        float f[10];
        bh8 v = *(const bh8*)&row[x0];
#pragma unroll
        for (int j = 0; j < 8; j++) f[j + 1] = bf2f(v[j]);
        f[0] = (x0 == 0) ? 0.f : bf2f(row[x0 - 1]);
        f[9] = (x0 == 120) ? 0.f : bf2f(row[x0 + 8]);
        float w0 = k1[ky * 3], wA = k1[ky * 3 + 1], wB = k1[ky * 3 + 2];
#pragma unroll
        for (int i = 0; i < 8; i++) acc[i] += f[i] * w0 + f[i + 1] * wA + f[i + 2] * wB;
      }
    }
    bh8 pk;
#pragma unroll
    for (int i = 0; i < 8; i++) pk[i] = f2bf(acc[i]);
    *(bh8*)&D[y * 136 + x0] = pk;
  }
  __syncthreads();

#pragma unroll
  for (int g = 0; g < 8; g++) {
    const int x0 = hf * 64 + g * 8;
    float acc[8], center[8];
#pragma unroll
    for (int i = 0; i < 8; i++) acc[i] = bias2;
#pragma unroll
    for (int ky = 0; ky < 3; ky++) {
      int yy = y + (ky - 1) * 2;
      if ((unsigned)yy < 128u) {
        const short* row = &D[yy * 136];
        float f[12];
        bh8 v = *(const bh8*)&row[x0];
#pragma unroll
        for (int j = 0; j < 8; j++) f[j + 2] = bf2f(v[j]);
        if (x0 == 0) { f[0] = 0.f; f[1] = 0.f; }
        else {
          unsigned lp = *(const unsigned*)&row[x0 - 2];
          f[0] = __builtin_bit_cast(float, lp << 16);
          f[1] = __builtin_bit_cast(float, lp & 0xffff0000u);
        }
        if (x0 == 120) { f[10] = 0.f; f[11] = 0.f; }
        else {
          unsigned rp = *(const unsigned*)&row[x0 + 8];
          f[10] = __builtin_bit_cast(float, rp << 16);
          f[11] = __builtin_bit_cast(float, rp & 0xffff0000u);
        }
        float w0 = k2[ky * 3], wA = k2[ky * 3 + 1], wB = k2[ky * 3 + 2];
#pragma unroll
        for (int i = 0; i < 8; i++) acc[i] += f[i] * w0 + f[i + 2] * wA + f[i + 4] * wB;
        if (ky == 1) {
#pragma unroll
          for (int i = 0; i < 8; i++) center[i] = f[i + 2];
        }
      }
    }
    bh8 pk;
#pragma unroll
    for (int i = 0; i < 8; i++) pk[i] = f2bf(center[i] + ds * acc[i]);
    *(bh8*)(outp + ((size_t)p << 14) + y * 128 + x0) = pk;
  }
}

// ---------------- fco GEMM + residual 2 -> out ----------------
__global__ __launch_bounds__(256) void gemm_fco(const short* __restrict__ h2,
                                                const short* __restrict__ wo,
                                                const float* __restrict__ wb,
                                                const float* __restrict__ x1,
                                                const float* __restrict__ ls2,
                                                const float* __restrict__ st,
                                                float* __restrict__ out) {
  __shared__ short As[128 * 40];
  __shared__ short Bs[96 * 40];
  const int m0 = blockIdx.x * 128, by = blockIdx.y, n0 = by * 96;
  const int b = m0 >> 14, l0 = m0 & 16383;
  const int tid = threadIdx.x, wid = tid >> 6, lane = tid & 63;
  const int g = lane >> 4, h = lane & 15;
  const int wm = wid >> 1, wn = wid & 1;
  fx4 acc[4][3];
#pragma unroll
  for (int i = 0; i < 4; i++)
#pragma unroll
    for (int j = 0; j < 3; j++) acc[i][j] = fzero();

  for (int kt = 0; kt < 16; kt++) {
    const int k0 = kt * 32;
#pragma unroll
    for (int i = 0; i < 2; i++) {
      int ch = tid + i * 256;
      int cc = ch & 31, lgrp = ch >> 5;
      bh8 v = *(const bh8*)(h2 + (((size_t)(b * 512 + k0 + cc)) << 14) + l0 + lgrp * 8);
#pragma unroll
      for (int j = 0; j < 8; j++) As[(lgrp * 8 + j) * 40 + cc] = v[j];
    }
    {
      int row = tid >> 2, sl = tid & 3;
      *(bh8*)&Bs[row * 40 + sl * 8] = *(const bh8*)(wo + (size_t)(n0 + row) * 512 + k0 + sl * 8);
      int ch = tid + 256;
      if (ch < 384) {
        row = ch >> 2; sl = ch & 3;
        *(bh8*)&Bs[row * 40 + sl * 8] = *(const bh8*)(wo + (size_t)(n0 + row) * 512 + k0 + sl * 8);
      }
    }
    __syncthreads();
    bh8 af[4];
#pragma unroll
    for (int mi = 0; mi < 4; mi++)
      af[mi] = *(bh8*)&As[(wm * 64 + mi * 16 + h) * 40 + g * 8];
#pragma unroll
    for (int ni = 0; ni < 3; ni++) {
      bh8 bf = *(bh8*)&Bs[(wn * 48 + ni * 16 + h) * 40 + g * 8];
#pragma unroll
      for (int mi = 0; mi < 4; mi++) acc[mi][ni] = mfma16(af[mi], bf, acc[mi][ni]);
    }
    __syncthreads();
  }
  float s2 = st[b * 2 + 1];
#pragma unroll
  for (int mi = 0; mi < 4; mi++)
#pragma unroll
    for (int ni = 0; ni < 3; ni++)
#pragma unroll
      for (int r = 0; r < 4; r++) {
        int row = m0 + wm * 64 + mi * 16 + g * 4 + r;
        int col = n0 + wn * 48 + ni * 16 + h;
        size_t di = (size_t)row * 192 + col;
        out[di] = x1[di] + s2 * ls2[col] * (acc[mi][ni][r] + wb[col]);
      }
}

extern "C" void kernel_launch(void* const* d_in, const int* in_sizes, int n_in,
                              void* d_out, int out_size, void* d_ws, size_t ws_size,
                              hipStream_t stream) {
  const float* x      = (const float*)d_in[0];
  const float* qkv_w  = (const float*)d_in[1];
  const float* qkv_b  = (const float*)d_in[2];
  const float* proj_w = (const float*)d_in[3];
  const float* proj_b = (const float*)d_in[4];
  const float* rpb    = (const float*)d_in[5];
  const float* n1_w   = (const float*)d_in[6];
  const float* n1_b   = (const float*)d_in[7];
  const float* ls1    = (const float*)d_in[8];
  const float* n2_w   = (const float*)d_in[9];
  const float* n2_b   = (const float*)d_in[10];
  const float* ls2    = (const float*)d_in[11];
  const float* fcgv_w = (const float*)d_in[12];
  const float* fcgv_b = (const float*)d_in[13];
  const float* dw_w   = (const float*)d_in[14];
  const float* dw_b   = (const float*)d_in[15];
  const float* dwd_w  = (const float*)d_in[16];
  const float* dwd_b  = (const float*)d_in[17];
  const float* dil    = (const float*)d_in[18];
  const float* fco_w  = (const float*)d_in[19];
  const float* fco_b  = (const float*)d_in[20];
  float* out = (float*)d_out;
  char* ws = (char*)d_ws;

  // workspace layout (bytes); peak usage ~70.7 MB
  short* wbuf = (short*)(ws + 0);           // 884736 B: [wq|wp|wg|wo]
  short* wq = wbuf;                          // elem off 0
  short* wp = wbuf + 110592;
  short* wg = wbuf + 147456;
  short* wo = wbuf + 344064;
  float* part  = (float*)(ws + 884736);     // 4096
  float* aff1  = (float*)(ws + 888832);     // 1536
  float* aff2  = (float*)(ws + 890368);     // 1536
  float* st1   = (float*)(ws + 891904);     // 64
  float* st2   = (float*)(ws + 891968);     // 64
  float* part2 = (float*)(ws + 892032);     // 4096
  short* xn  = (short*)(ws + 1048576);      // 12.58 MB (dead after qkv)
  short* bt  = (short*)(ws + 13631488);     // 1.77 MB  (dead after attn)
  short* qb  = (short*)(ws + 15400960);     // 12.58 MB (dead after attn)
  short* kb  = (short*)(ws + 27983872);     // 12.58 MB (dead after attn)
  short* vb  = (short*)(ws + 40566784);     // 12.58 MB (dead after attn)
  short* ao  = (short*)(ws + 53149696);     // 12.58 MB (dead after proj)
  float* x1  = (float*)(ws + 1048576);      // 25.17 MB (over xn+bt+qb-head)
  short* x1n = (short*)(ws + 26214400);     // 12.58 MB (over qb-tail+kb)
  short* hp  = (short*)(ws + 40566784);     // 33.55 MB (over vb+ao); in-place dw

  cvt_w<<<216, 256, 0, stream>>>(qkv_w, proj_w, fcgv_w, fco_w, wbuf);
  iln_partial<<<512, 256, 0, stream>>>(x, part);
  iln_final<<<2, 256, 0, stream>>>(part, n1_w, n1_b, aff1, st1);
  cvt_aff<<<3072, 256, 0, stream>>>(x, aff1, xn);
  bias_gen<<<216, 256, 0, stream>>>(rpb, bt);
  gemm_qkv<<<dim3(256, 6), 256, 0, stream>>>(xn, wq, qkv_b, qb, kb, vb);
  attn_kernel<<<dim3(128, 6), 256, 0, stream>>>(qb, kb, vb, bt, ao);
  gemm_proj<<<dim3(256, 2), 256, 0, stream>>>(ao, wp, proj_b, x, ls1, st1, x1, part2);
  iln_final<<<2, 256, 0, stream>>>(part2, n2_w, n2_b, aff2, st2);
  cvt_aff<<<3072, 256, 0, stream>>>(x1, aff2, x1n);
  gemm_fcgv<<<dim3(256, 8), 256, 0, stream>>>(x1n, wg, fcgv_b, hp);
  dw_fused<<<1024, 256, 0, stream>>>(hp, dw_w, dw_b, dwd_w, dwd_b, dil, hp);
  gemm_fco<<<dim3(256, 2), 256, 0, stream>>>(hp, wo, fco_b, x1, ls2, st2, out);
}

// Round 5
// 189.656 us; speedup vs baseline: 2.5302x; 1.0013x over previous
//
#include <hip/hip_runtime.h>

#define DI __device__ __forceinline__

typedef __attribute__((ext_vector_type(8))) short bh8;
typedef __attribute__((ext_vector_type(4))) float fx4;
typedef __attribute__((ext_vector_type(16))) float fx16;

DI short f2bf(float f) {
  unsigned u = __builtin_bit_cast(unsigned, f);
  u += 0x7FFFu + ((u >> 16) & 1u);
  return (short)(u >> 16);
}
DI float bf2f(short s) {
  unsigned u = ((unsigned)(unsigned short)s) << 16;
  return __builtin_bit_cast(float, u);
}
DI fx4 mfma16(bh8 a, bh8 b, fx4 c) {
  return __builtin_amdgcn_mfma_f32_16x16x32_bf16(a, b, c, 0, 0, 0);
}
DI fx16 mfma32(bh8 a, bh8 b, fx16 c) {
  return __builtin_amdgcn_mfma_f32_32x32x16_bf16(a, b, c, 0, 0, 0);
}
DI fx4 fzero() { fx4 z = {0.f, 0.f, 0.f, 0.f}; return z; }

DI float fexp2(float x) {
#if __has_builtin(__builtin_amdgcn_exp2f)
  return __builtin_amdgcn_exp2f(x);
#else
  return exp2f(x);
#endif
}

DI bh8 pack8(const float* src) {
  fx4 v0 = *(const fx4*)src;
  fx4 v1 = *(const fx4*)(src + 4);
  bh8 pk;
#pragma unroll
  for (int j = 0; j < 4; j++) { pk[j] = f2bf(v0[j]); pk[j + 4] = f2bf(v1[j]); }
  return pk;
}
DI bh8 pack8_aff(const float* src, const float* affc) {
  fx4 v0 = *(const fx4*)src;
  fx4 v1 = *(const fx4*)(src + 4);
  bh8 pk;
#pragma unroll
  for (int j = 0; j < 4; j++) {
    pk[j]     = f2bf(v0[j] * affc[2 * j]       + affc[2 * j + 1]);
    pk[j + 4] = f2bf(v1[j] * affc[2 * (j + 4)] + affc[2 * (j + 4) + 1]);
  }
  return pk;
}

// ---------------- holistic LN stats (pass over x only) ----------------
__global__ __launch_bounds__(256) void iln_partial(const float* __restrict__ x,
                                                   float* __restrict__ part) {
  const int blk = blockIdx.x, tid = threadIdx.x;
  const fx4* p = (const fx4*)(x + (size_t)blk * 12288);
  float s = 0.f, s2 = 0.f;
#pragma unroll
  for (int i = 0; i < 12; i++) {
    fx4 v = p[i * 256 + tid];
    s  += v[0] + v[1] + v[2] + v[3];
    s2 += v[0] * v[0] + v[1] * v[1] + v[2] * v[2] + v[3] * v[3];
  }
  __shared__ float sm[512];
  sm[tid] = s; sm[256 + tid] = s2;
  __syncthreads();
  for (int st = 128; st > 0; st >>= 1) {
    if (tid < st) { sm[tid] += sm[tid + st]; sm[256 + tid] += sm[256 + tid + st]; }
    __syncthreads();
  }
  if (tid == 0) { part[blk * 2] = sm[0]; part[blk * 2 + 1] = sm[256]; }
}

__global__ __launch_bounds__(256) void iln_final(const float* __restrict__ part,
                                                 const float* __restrict__ w,
                                                 const float* __restrict__ bias,
                                                 float* __restrict__ aff,
                                                 float* __restrict__ st) {
  const int b = blockIdx.x, tid = threadIdx.x;
  __shared__ float sm[512];
  sm[tid]       = part[(b * 256 + tid) * 2];
  sm[256 + tid] = part[(b * 256 + tid) * 2 + 1];
  __syncthreads();
  for (int s = 128; s > 0; s >>= 1) {
    if (tid < s) { sm[tid] += sm[tid + s]; sm[256 + tid] += sm[256 + tid + s]; }
    __syncthreads();
  }
  const float invn = 1.f / 3145728.f;
  float mean = sm[0] * invn;
  float var  = sm[256] * invn - mean * mean;
  float scale = fminf(sqrtf(var + 1e-6f), 2.f);
  if (tid < 192) {
    float a = w[tid] / scale;
    aff[(b * 192 + tid) * 2]     = a;
    aff[(b * 192 + tid) * 2 + 1] = bias[tid] - mean * a;
  }
  if (tid == 0) { st[b * 2] = mean; st[b * 2 + 1] = scale; }
}

// ---------------- weight convert ----------------
__global__ __launch_bounds__(256) void cvt_w(const float* __restrict__ qkv_w,
                                             const float* __restrict__ proj_w,
                                             const float* __restrict__ fcgv_w,
                                             const float* __restrict__ fco_w,
                                             short* __restrict__ wbuf) {
  int t = blockIdx.x * 256 + threadIdx.x;
  int off = t * 8;
  const float* src;
  if (off < 110592)       src = qkv_w + off;
  else if (off < 147456)  src = proj_w + (off - 110592);
  else if (off < 344064)  src = fcgv_w + (off - 147456);
  else                    src = fco_w + (off - 344064);
  *(bh8*)(wbuf + off) = pack8(src);
}

// ---------------- activation convert with affine ----------------
__global__ __launch_bounds__(256) void cvt_aff(const float* __restrict__ src,
                                               const float* __restrict__ aff,
                                               short* __restrict__ dst) {
  int t = blockIdx.x * 256 + threadIdx.x;
  int row = t / 24;
  int c0 = (t - row * 24) * 8;
  const float* affp = aff + (row >> 14) * 384 + c0 * 2;
  *(bh8*)(dst + (size_t)t * 8) = pack8_aff(src + (size_t)row * 192 + c0, affp);
}

// ---------------- bias table gen: f32 accumulator layout, times log2(e) ----------------
// fx4 index: ((((head*4+w)*9+kc)*4 + ki*2+qi)*4 + j)*64 + lane ; holds st[r=4j..4j+3]
__global__ __launch_bounds__(256) void bias_gen(const float* __restrict__ rpb,
                                                float* __restrict__ btf) {
  int t = blockIdx.x * 256 + threadIdx.x;  // 55296 threads
  int lane = t & 63;
  int u = t >> 6;
  int qi = u & 1; int u2 = u >> 1;
  int ki = u2 & 1; u2 >>= 1;
  int kc = u2 % 9; u2 = u2 / 9;
  int w = u2 & 3, head = u2 >> 2;
  int c = lane & 31, hi = lane >> 5;
  int q = w * 64 + qi * 32 + c;
  int qterm = (q >> 4) * 39 + (q & 15);
  (void)ki; (void)kc;
  float o[16];
#pragma unroll
  for (int r = 0; r < 16; r++) {
    int k = (u & 0x3c) ? 0 : 0;  // placeholder no-op
    (void)k;
    int kk = ((u >> 2) % 9) * 64 + ((u >> 1) & 1) * 32 + (r & 3) + 8 * (r >> 2) + 4 * hi;
    int ky = (kk * 2731) >> 16;
    int kx = kk - ky * 24;
    int idx = ky * 39 + kx + 600 - qterm;
    o[r] = rpb[idx * 6 + head] * 1.4426950408889634f;
  }
  fx4* dst = (fx4*)btf;
#pragma unroll
  for (int j = 0; j < 4; j++) {
    fx4 v = {o[4 * j], o[4 * j + 1], o[4 * j + 2], o[4 * j + 3]};
    dst[((size_t)u * 4 + j) * 64 + lane] = v;
  }
}

// ---------------- QKV GEMM: K rows pre-scaled by SCALE*log2e ----------------
__global__ __launch_bounds__(256) void gemm_qkv(const short* __restrict__ xn,
                                                const short* __restrict__ wq,
                                                const float* __restrict__ wb,
                                                short* __restrict__ qb,
                                                short* __restrict__ kb,
                                                short* __restrict__ vb) {
  __shared__ short As[128 * 40];
  __shared__ short Bs[96 * 40];
  const int m0 = blockIdx.x * 128, by = blockIdx.y, n0 = by * 96;
  const int tid = threadIdx.x, wid = tid >> 6, lane = tid & 63;
  const int g = lane >> 4, h = lane & 15;
  const int wm = wid >> 1, wn = wid & 1;
  fx4 acc[4][3];
#pragma unroll
  for (int i = 0; i < 4; i++)
#pragma unroll
    for (int j = 0; j < 3; j++) acc[i][j] = fzero();

  for (int kt = 0; kt < 6; kt++) {
    const int k0 = kt * 32;
#pragma unroll
    for (int i = 0; i < 2; i++) {
      int ch = tid + i * 256;
      int row = ch >> 2, sl = ch & 3;
      *(bh8*)&As[row * 40 + sl * 8] = *(const bh8*)(xn + (size_t)(m0 + row) * 192 + k0 + sl * 8);
    }
    {
      int row = tid >> 2, sl = tid & 3;
      *(bh8*)&Bs[row * 40 + sl * 8] = *(const bh8*)(wq + (size_t)(n0 + row) * 192 + k0 + sl * 8);
      int ch = tid + 256;
      if (ch < 384) {
        row = ch >> 2; sl = ch & 3;
        *(bh8*)&Bs[row * 40 + sl * 8] = *(const bh8*)(wq + (size_t)(n0 + row) * 192 + k0 + sl * 8);
      }
    }
    __syncthreads();
    bh8 af[4];
#pragma unroll
    for (int mi = 0; mi < 4; mi++)
      af[mi] = *(bh8*)&As[(wm * 64 + mi * 16 + h) * 40 + g * 8];
#pragma unroll
    for (int ni = 0; ni < 3; ni++) {
      bh8 bf = *(bh8*)&Bs[(wn * 48 + ni * 16 + h) * 40 + g * 8];
#pragma unroll
      for (int mi = 0; mi < 4; mi++) acc[mi][ni] = mfma16(af[mi], bf, acc[mi][ni]);
    }
    __syncthreads();
  }
  const int seg = by >> 1;
  short* dst = (seg == 0) ? qb : (seg == 1 ? kb : vb);
  const float sc = (seg == 1) ? 0.25503486f : 1.0f;  // SCALE * log2(e) folded into K
  const int colbase = (by & 1) * 96;
#pragma unroll
  for (int mi = 0; mi < 4; mi++)
#pragma unroll
    for (int ni = 0; ni < 3; ni++)
#pragma unroll
      for (int r = 0; r < 4; r++) {
        int row = m0 + wm * 64 + mi * 16 + g * 4 + r;
        int col = colbase + wn * 48 + ni * 16 + h;
        dst[(size_t)row * 192 + col] = f2bf((acc[mi][ni][r] + wb[seg * 192 + col]) * sc);
      }
}

// ---------------- attention: swapped-QK, f32 bias C-init, exp2, permlane, K/V dbuf ----------------
__global__ __launch_bounds__(256, 3) void attn_kernel(const short* __restrict__ qb,
                                                      const short* __restrict__ kb,
                                                      const short* __restrict__ vb,
                                                      const float* __restrict__ btf,
                                                      short* __restrict__ ao) {
  __shared__ short K_lds[2][64 * 40];
  __shared__ short Vt_lds[2][32 * 72];
  __shared__ float l_lds[256];
  const int tid = threadIdx.x;
  const int win = blockIdx.x, head = blockIdx.y;
  const int b = win >> 6, wy = (win >> 3) & 7, wx = win & 7;
  const int w = tid >> 6, lane = tid & 63, c = lane & 31, hi = lane >> 5;

  bh8 qf[2][2];
#pragma unroll
  for (int qi = 0; qi < 2; qi++) {
    int ql = w * 64 + qi * 32 + c;
    size_t gl = (size_t)(b * 16384 + (wy * 16 + (ql >> 4)) * 128 + wx * 16 + (ql & 15));
#pragma unroll
    for (int ds = 0; ds < 2; ds++)
      qf[qi][ds] = *(const bh8*)(qb + gl * 192 + head * 32 + ds * 16 + hi * 8);
  }
  float l_run[2] = {0.f, 0.f};
  fx16 out[2];
#pragma unroll
  for (int r = 0; r < 16; r++) { out[0][r] = 0.f; out[1][r] = 0.f; }

  const fx4* btf4 = (const fx4*)btf;
  const int hw9 = (head * 4 + w) * 9;

  const int kl_a = tid >> 2, part_a = tid & 3;
  const int kl_b = tid & 63, hg_b = tid >> 6;

  // gather loads for chunk kc into registers
  auto load_kv = [&](int kc, bh8& kr, bh8& vr) {
    int key = kc * 64 + kl_a;
    int ky = key / 24, kx = key - ky * 24;
    int py = wy * 16 - 4 + ky, px = wx * 16 - 4 + kx;
    bh8 kv = {};
    if ((unsigned)py < 128u && (unsigned)px < 128u)
      kv = *(const bh8*)(kb + ((size_t)(b * 16384 + py * 128 + px)) * 192 + head * 32 + part_a * 8);
    kr = kv;
    int key2 = kc * 64 + kl_b;
    int ky2 = key2 / 24, kx2 = key2 - ky2 * 24;
    int py2 = wy * 16 - 4 + ky2, px2 = wx * 16 - 4 + kx2;
    bh8 vv = {};
    if ((unsigned)py2 < 128u && (unsigned)px2 < 128u)
      vv = *(const bh8*)(vb + ((size_t)(b * 16384 + py2 * 128 + px2)) * 192 + head * 32 + hg_b * 8);
    vr = vv;
  };

  {
    bh8 k0r, v0r;
    load_kv(0, k0r, v0r);
    *(bh8*)&K_lds[0][kl_a * 40 + part_a * 8] = k0r;
#pragma unroll
    for (int j = 0; j < 8; j++) Vt_lds[0][(hg_b * 8 + j) * 72 + kl_b] = v0r[j];
  }
  int cur = 0;

  for (int kc = 0; kc < 9; kc++) {
    bh8 kn, vn;
    if (kc < 8) load_kv(kc + 1, kn, vn);
    __syncthreads();

    const fx4* base_kc = btf4 + (size_t)(hw9 + kc) * 1024 + lane;
#pragma unroll
    for (int ki = 0; ki < 2; ki++) {
      fx16 st[2];
#pragma unroll
      for (int qi = 0; qi < 2; qi++) {
        const fx4* bp = base_kc + (ki * 2 + qi) * 256;
        fx4 b0 = bp[0], b1 = bp[64], b2 = bp[128], b3 = bp[192];
#pragma unroll
        for (int m = 0; m < 4; m++) {
          st[qi][m]      = b0[m];
          st[qi][4 + m]  = b1[m];
          st[qi][8 + m]  = b2[m];
          st[qi][12 + m] = b3[m];
        }
      }
#pragma unroll
      for (int ds = 0; ds < 2; ds++) {
        bh8 kf = *(bh8*)&K_lds[cur][(ki * 32 + c) * 40 + ds * 16 + hi * 8];
        st[0] = mfma32(kf, qf[0][ds], st[0]);
        st[1] = mfma32(kf, qf[1][ds], st[1]);
      }
#pragma unroll
      for (int qi = 0; qi < 2; qi++) {
        float s = 0.f;
#pragma unroll
        for (int r = 0; r < 16; r++) {
          float p = fexp2(st[qi][r]);
          st[qi][r] = p;
          s += p;
        }
        l_run[qi] += s;
      }
      int dwq[2][2][4];
#pragma unroll
      for (int qi = 0; qi < 2; qi++)
#pragma unroll
        for (int k1 = 0; k1 < 2; k1++)
#pragma unroll
          for (int p01 = 0; p01 < 2; p01++) {
            int rA = 2 * p01 + 8 * k1;
            int A, Bv;
            asm("v_cvt_pk_bf16_f32 %0, %1, %2" : "=v"(A)  : "v"(st[qi][rA]),     "v"(st[qi][rA + 1]));
            asm("v_cvt_pk_bf16_f32 %0, %1, %2" : "=v"(Bv) : "v"(st[qi][rA + 4]), "v"(st[qi][rA + 5]));
#if __has_builtin(__builtin_amdgcn_permlane32_swap)
            auto pr = __builtin_amdgcn_permlane32_swap((unsigned)A, (unsigned)Bv, false, false);
            dwq[qi][k1][p01]     = (int)pr[0];
            dwq[qi][k1][p01 + 2] = (int)pr[1];
#else
            int Ax = __shfl_xor(A, 32);
            int Bx = __shfl_xor(Bv, 32);
            dwq[qi][k1][p01]     = hi ? Bx : A;
            dwq[qi][k1][p01 + 2] = hi ? Bv : Ax;
#endif
          }
#pragma unroll
      for (int k1 = 0; k1 < 2; k1++) {
        bh8 bv2 = *(bh8*)&Vt_lds[cur][c * 72 + (ki * 2 + k1) * 16 + hi * 8];
#pragma unroll
        for (int qi = 0; qi < 2; qi++) {
          int4 t4 = {dwq[qi][k1][0], dwq[qi][k1][1], dwq[qi][k1][2], dwq[qi][k1][3]};
          out[qi] = mfma32(__builtin_bit_cast(bh8, t4), bv2, out[qi]);
        }
      }
    }
    if (kc < 8) {
      *(bh8*)&K_lds[cur ^ 1][kl_a * 40 + part_a * 8] = kn;
#pragma unroll
      for (int j = 0; j < 8; j++) Vt_lds[cur ^ 1][(hg_b * 8 + j) * 72 + kl_b] = vn[j];
    }
    cur ^= 1;
  }
#pragma unroll
  for (int qi = 0; qi < 2; qi++) {
    float lp = l_run[qi] + __shfl_xor(l_run[qi], 32);
    l_lds[w * 64 + qi * 32 + c] = 1.f / lp;
  }
  __syncthreads();
#pragma unroll
  for (int qi = 0; qi < 2; qi++)
#pragma unroll
    for (int r = 0; r < 16; r++) {
      int row = (r & 3) + 8 * (r >> 2) + 4 * hi;
      float val = out[qi][r] * l_lds[w * 64 + qi * 32 + row];
      int ql = w * 64 + qi * 32 + row;
      ao[((size_t)(win * 256 + ql)) * 192 + head * 32 + c] = f2bf(val);
    }
}

// ---------------- proj GEMM + window reverse + residual 1 + iln2 partials ----------------
__global__ __launch_bounds__(256) void gemm_proj(const short* __restrict__ ao,
                                                 const short* __restrict__ wp,
                                                 const float* __restrict__ wb,
                                                 const float* __restrict__ x,
                                                 const float* __restrict__ ls1,
                                                 const float* __restrict__ st,
                                                 float* __restrict__ x1,
                                                 float* __restrict__ part2) {
  __shared__ short As[128 * 40];
  __shared__ short Bs[96 * 40];
  const int m0 = blockIdx.x * 128, by = blockIdx.y, n0 = by * 96;
  const int tid = threadIdx.x, wid = tid >> 6, lane = tid & 63;
  const int g = lane >> 4, h = lane & 15;
  const int wm = wid >> 1, wn = wid & 1;
  fx4 acc[4][3];
#pragma unroll
  for (int i = 0; i < 4; i++)
#pragma unroll
    for (int j = 0; j < 3; j++) acc[i][j] = fzero();

  for (int kt = 0; kt < 6; kt++) {
    const int k0 = kt * 32;
#pragma unroll
    for (int i = 0; i < 2; i++) {
      int ch = tid + i * 256;
      int row = ch >> 2, sl = ch & 3;
      *(bh8*)&As[row * 40 + sl * 8] = *(const bh8*)(ao + (size_t)(m0 + row) * 192 + k0 + sl * 8);
    }
    {
      int row = tid >> 2, sl = tid & 3;
      *(bh8*)&Bs[row * 40 + sl * 8] = *(const bh8*)(wp + (size_t)(n0 + row) * 192 + k0 + sl * 8);
      int ch = tid + 256;
      if (ch < 384) {
        row = ch >> 2; sl = ch & 3;
        *(bh8*)&Bs[row * 40 + sl * 8] = *(const bh8*)(wp + (size_t)(n0 + row) * 192 + k0 + sl * 8);
      }
    }
    __syncthreads();
    bh8 af[4];
#pragma unroll
    for (int mi = 0; mi < 4; mi++)
      af[mi] = *(bh8*)&As[(wm * 64 + mi * 16 + h) * 40 + g * 8];
#pragma unroll
    for (int ni = 0; ni < 3; ni++) {
      bh8 bf = *(bh8*)&Bs[(wn * 48 + ni * 16 + h) * 40 + g * 8];
#pragma unroll
      for (int mi = 0; mi < 4; mi++) acc[mi][ni] = mfma16(af[mi], bf, acc[mi][ni]);
    }
    __syncthreads();
  }
  float ps = 0.f, ps2 = 0.f;
#pragma unroll
  for (int mi = 0; mi < 4; mi++)
#pragma unroll
    for (int ni = 0; ni < 3; ni++)
#pragma unroll
      for (int r = 0; r < 4; r++) {
        int grow = m0 + wm * 64 + mi * 16 + g * 4 + r;
        int win = grow >> 8, q = grow & 255;
        int bb = win >> 6, wy = (win >> 3) & 7, wxx = win & 7;
        int l = (wy * 16 + (q >> 4)) * 128 + wxx * 16 + (q & 15);
        int col = n0 + wn * 48 + ni * 16 + h;
        size_t di = ((size_t)(bb * 16384 + l)) * 192 + col;
        float s1 = st[bb * 2 + 1];
        float val = x[di] + s1 * ls1[col] * (acc[mi][ni][r] + wb[col]);
        x1[di] = val;
        ps += val;
        ps2 += val * val;
      }
  float* red = (float*)As;
  red[tid] = ps; red[256 + tid] = ps2;
  __syncthreads();
  for (int s = 128; s > 0; s >>= 1) {
    if (tid < s) { red[tid] += red[tid + s]; red[256 + tid] += red[256 + tid + s]; }
    __syncthreads();
  }
  if (tid == 0) {
    int pi = blockIdx.x * 2 + by;
    part2[pi * 2] = red[0];
    part2[pi * 2 + 1] = red[256];
  }
}

// ---------------- fcgv GEMM (dual gate/val) + SiLU -> planar hp ----------------
__global__ __launch_bounds__(256) void gemm_fcgv(const short* __restrict__ x1n,
                                                 const short* __restrict__ wg,
                                                 const float* __restrict__ wb,
                                                 short* __restrict__ hp) {
  __shared__ short smem[128 * 40 + 128 * 40];
  short* As = smem;
  short* Bs = smem + 128 * 40;
  const int m0 = blockIdx.x * 128, n0 = blockIdx.y * 64;
  const int b = m0 >> 14, l0 = m0 & 16383;
  const int tid = threadIdx.x, wid = tid >> 6, lane = tid & 63;
  const int g = lane >> 4, h = lane & 15;
  const int wm = wid >> 1, wn = wid & 1;
  fx4 accg[4][2], accv[4][2];
#pragma unroll
  for (int i = 0; i < 4; i++)
#pragma unroll
    for (int j = 0; j < 2; j++) { accg[i][j] = fzero(); accv[i][j] = fzero(); }

  for (int kt = 0; kt < 6; kt++) {
    const int k0 = kt * 32;
#pragma unroll
    for (int i = 0; i < 2; i++) {
      int ch = tid + i * 256;
      int row = ch >> 2, sl = ch & 3;
      *(bh8*)&As[row * 40 + sl * 8] = *(const bh8*)(x1n + (size_t)(m0 + row) * 192 + k0 + sl * 8);
    }
#pragma unroll
    for (int i = 0; i < 2; i++) {
      int ch = tid + i * 256;
      int row = ch >> 2, sl = ch & 3;
      int wrow = (row < 64) ? (n0 + row) : (512 + n0 + row - 64);
      *(bh8*)&Bs[row * 40 + sl * 8] = *(const bh8*)(wg + (size_t)wrow * 192 + k0 + sl * 8);
    }
    __syncthreads();
    bh8 af[4];
#pragma unroll
    for (int mi = 0; mi < 4; mi++)
      af[mi] = *(bh8*)&As[(wm * 64 + mi * 16 + h) * 40 + g * 8];
#pragma unroll
    for (int ni = 0; ni < 2; ni++) {
      bh8 bg = *(bh8*)&Bs[(wn * 32 + ni * 16 + h) * 40 + g * 8];
      bh8 bv = *(bh8*)&Bs[(64 + wn * 32 + ni * 16 + h) * 40 + g * 8];
#pragma unroll
      for (int mi = 0; mi < 4; mi++) {
        accg[mi][ni] = mfma16(af[mi], bg, accg[mi][ni]);
        accv[mi][ni] = mfma16(af[mi], bv, accv[mi][ni]);
      }
    }
    __syncthreads();
  }
  short hs[4][2][4];
#pragma unroll
  for (int mi = 0; mi < 4; mi++)
#pragma unroll
    for (int ni = 0; ni < 2; ni++)
#pragma unroll
      for (int r = 0; r < 4; r++) {
        int colg = n0 + wn * 32 + ni * 16 + h;
        float gv = accg[mi][ni][r] + wb[colg];
        float vv = accv[mi][ni][r] + wb[512 + colg];
        hs[mi][ni][r] = f2bf(gv / (1.f + __expf(-gv)) * vv);
      }
  short* T = smem;
#pragma unroll
  for (int mi = 0; mi < 4; mi++)
#pragma unroll
    for (int ni = 0; ni < 2; ni++)
#pragma unroll
      for (int r = 0; r < 4; r++) {
        int cc = wn * 32 + ni * 16 + h;
        int rl = wm * 64 + mi * 16 + g * 4 + r;
        T[cc * 136 + rl] = hs[mi][ni][r];
      }
  __syncthreads();
#pragma unroll
  for (int i = 0; i < 4; i++) {
    int ch = tid + i * 256;
    int cc = ch >> 4, lg = ch & 15;
    bh8 v = *(bh8*)&T[cc * 136 + lg * 8];
    *(bh8*)(hp + (((size_t)(b * 512 + n0 + cc)) << 14) + l0 + lg * 8) = v;
  }
}

// ---------------- fused depthwise convs (in-place safe: plane-local) ----------------
__global__ __launch_bounds__(256, 2) void dw_fused(const short* __restrict__ in,
                                                   const float* __restrict__ w1,
                                                   const float* __restrict__ b1,
                                                   const float* __restrict__ w2,
                                                   const float* __restrict__ b2,
                                                   const float* __restrict__ dsc,
                                                   short* __restrict__ outp) {
  __shared__ short P[136 * 128];
  __shared__ short D[136 * 128];
  const int p = blockIdx.x, c = p & 511;
  const int tid = threadIdx.x;
#pragma unroll
  for (int i = 0; i < 8; i++) {
    int gs = i * 256 + tid;
    int yy = gs >> 4, sl = gs & 15;
    bh8 v = *(const bh8*)(in + ((size_t)p << 14) + gs * 8);
    *(bh8*)&P[yy * 136 + sl * 8] = v;
  }
  float k1[9], k2[9];
#pragma unroll
  for (int j = 0; j < 9; j++) { k1[j] = w1[c * 9 + j]; k2[j] = w2[c * 9 + j]; }
  const float bias1 = b1[c], bias2 = b2[c], ds = dsc[0];
  const int y = tid >> 1, hf = tid & 1;
  __syncthreads();

#pragma unroll
  for (int g = 0; g < 8; g++) {
    const int x0 = hf * 64 + g * 8;
    float acc[8];
#pragma unroll
    for (int i = 0; i < 8; i++) acc[i] = bias1;
#pragma unroll
    for (int ky = 0; ky < 3; ky++) {
      int yy = y + ky - 1;
      if ((unsigned)yy < 128u) {
        const short* row = &P[yy * 136];
        float f[10];
        bh8 v = *(const bh8*)&row[x0];
#pragma unroll
        for (int j = 0; j < 8; j++) f[j + 1] = bf2f(v[j]);
        f[0] = (x0 == 0) ? 0.f : bf2f(row[x0 - 1]);
        f[9] = (x0 == 120) ? 0.f : bf2f(row[x0 + 8]);
        float w0 = k1[ky * 3], wA = k1[ky * 3 + 1], wB = k1[ky * 3 + 2];
#pragma unroll
        for (int i = 0; i < 8; i++) acc[i] += f[i] * w0 + f[i + 1] * wA + f[i + 2] * wB;
      }
    }
    bh8 pk;
#pragma unroll
    for (int i = 0; i < 8; i++) pk[i] = f2bf(acc[i]);
    *(bh8*)&D[y * 136 + x0] = pk;
  }
  __syncthreads();

#pragma unroll
  for (int g = 0; g < 8; g++) {
    const int x0 = hf * 64 + g * 8;
    float acc[8], center[8];
#pragma unroll
    for (int i = 0; i < 8; i++) acc[i] = bias2;
#pragma unroll
    for (int ky = 0; ky < 3; ky++) {
      int yy = y + (ky - 1) * 2;
      if ((unsigned)yy < 128u) {
        const short* row = &D[yy * 136];
        float f[12];
        bh8 v = *(const bh8*)&row[x0];
#pragma unroll
        for (int j = 0; j < 8; j++) f[j + 2] = bf2f(v[j]);
        if (x0 == 0) { f[0] = 0.f; f[1] = 0.f; }
        else {
          unsigned lp = *(const unsigned*)&row[x0 - 2];
          f[0] = __builtin_bit_cast(float, lp << 16);
          f[1] = __builtin_bit_cast(float, lp & 0xffff0000u);
        }
        if (x0 == 120) { f[10] = 0.f; f[11] = 0.f; }
        else {
          unsigned rp = *(const unsigned*)&row[x0 + 8];
          f[10] = __builtin_bit_cast(float, rp << 16);
          f[11] = __builtin_bit_cast(float, rp & 0xffff0000u);
        }
        float w0 = k2[ky * 3], wA = k2[ky * 3 + 1], wB = k2[ky * 3 + 2];
#pragma unroll
        for (int i = 0; i < 8; i++) acc[i] += f[i] * w0 + f[i + 2] * wA + f[i + 4] * wB;
        if (ky == 1) {
#pragma unroll
          for (int i = 0; i < 8; i++) center[i] = f[i + 2];
        }
      }
    }
    bh8 pk;
#pragma unroll
    for (int i = 0; i < 8; i++) pk[i] = f2bf(center[i] + ds * acc[i]);
    *(bh8*)(outp + ((size_t)p << 14) + y * 128 + x0) = pk;
  }
}

// ---------------- fco GEMM + residual 2 -> out ----------------
__global__ __launch_bounds__(256) void gemm_fco(const short* __restrict__ h2,
                                                const short* __restrict__ wo,
                                                const float* __restrict__ wb,
                                                const float* __restrict__ x1,
                                                const float* __restrict__ ls2,
                                                const float* __restrict__ st,
                                                float* __restrict__ out) {
  __shared__ short As[128 * 40];
  __shared__ short Bs[96 * 40];
  const int m0 = blockIdx.x * 128, by = blockIdx.y, n0 = by * 96;
  const int b = m0 >> 14, l0 = m0 & 16383;
  const int tid = threadIdx.x, wid = tid >> 6, lane = tid & 63;
  const int g = lane >> 4, h = lane & 15;
  const int wm = wid >> 1, wn = wid & 1;
  const int cp = tid & 15, lg = tid >> 4;
  fx4 acc[4][3];
#pragma unroll
  for (int i = 0; i < 4; i++)
#pragma unroll
    for (int j = 0; j < 3; j++) acc[i][j] = fzero();

  for (int kt = 0; kt < 16; kt++) {
    const int k0 = kt * 32;
    {
      const short* basep = h2 + (((size_t)(b * 512 + k0 + 2 * cp)) << 14) + l0 + lg * 8;
      bh8 v0 = *(const bh8*)basep;
      bh8 v1 = *(const bh8*)(basep + 16384);
#pragma unroll
      for (int j = 0; j < 8; j++) {
        unsigned pkv = (unsigned)(unsigned short)v0[j] | (((unsigned)(unsigned short)v1[j]) << 16);
        *(unsigned*)&As[(lg * 8 + j) * 40 + 2 * cp] = pkv;
      }
    }
    {
      int row = tid >> 2, sl = tid & 3;
      *(bh8*)&Bs[row * 40 + sl * 8] = *(const bh8*)(wo + (size_t)(n0 + row) * 512 + k0 + sl * 8);
      int ch = tid + 256;
      if (ch < 384) {
        row = ch >> 2; sl = ch & 3;
        *(bh8*)&Bs[row * 40 + sl * 8] = *(const bh8*)(wo + (size_t)(n0 + row) * 512 + k0 + sl * 8);
      }
    }
    __syncthreads();
    bh8 af[4];
#pragma unroll
    for (int mi = 0; mi < 4; mi++)
      af[mi] = *(bh8*)&As[(wm * 64 + mi * 16 + h) * 40 + g * 8];
#pragma unroll
    for (int ni = 0; ni < 3; ni++) {
      bh8 bf = *(bh8*)&Bs[(wn * 48 + ni * 16 + h) * 40 + g * 8];
#pragma unroll
      for (int mi = 0; mi < 4; mi++) acc[mi][ni] = mfma16(af[mi], bf, acc[mi][ni]);
    }
    __syncthreads();
  }
  float s2 = st[b * 2 + 1];
#pragma unroll
  for (int mi = 0; mi < 4; mi++)
#pragma unroll
    for (int ni = 0; ni < 3; ni++)
#pragma unroll
      for (int r = 0; r < 4; r++) {
        int row = m0 + wm * 64 + mi * 16 + g * 4 + r;
        int col = n0 + wn * 48 + ni * 16 + h;
        size_t di = (size_t)row * 192 + col;
        out[di] = x1[di] + s2 * ls2[col] * (acc[mi][ni][r] + wb[col]);
      }
}

extern "C" void kernel_launch(void* const* d_in, const int* in_sizes, int n_in,
                              void* d_out, int out_size, void* d_ws, size_t ws_size,
                              hipStream_t stream) {
  const float* x      = (const float*)d_in[0];
  const float* qkv_w  = (const float*)d_in[1];
  const float* qkv_b  = (const float*)d_in[2];
  const float* proj_w = (const float*)d_in[3];
  const float* proj_b = (const float*)d_in[4];
  const float* rpb    = (const float*)d_in[5];
  const float* n1_w   = (const float*)d_in[6];
  const float* n1_b   = (const float*)d_in[7];
  const float* ls1    = (const float*)d_in[8];
  const float* n2_w   = (const float*)d_in[9];
  const float* n2_b   = (const float*)d_in[10];
  const float* ls2    = (const float*)d_in[11];
  const float* fcgv_w = (const float*)d_in[12];
  const float* fcgv_b = (const float*)d_in[13];
  const float* dw_w   = (const float*)d_in[14];
  const float* dw_b   = (const float*)d_in[15];
  const float* dwd_w  = (const float*)d_in[16];
  const float* dwd_b  = (const float*)d_in[17];
  const float* dil    = (const float*)d_in[18];
  const float* fco_w  = (const float*)d_in[19];
  const float* fco_b  = (const float*)d_in[20];
  float* out = (float*)d_out;
  char* ws = (char*)d_ws;

  // workspace layout (bytes); peak ~76 MB
  short* wbuf = (short*)(ws + 0);            // 884736 B
  short* wq = wbuf;
  short* wp = wbuf + 110592;
  short* wg = wbuf + 147456;
  short* wo = wbuf + 344064;
  float* part  = (float*)(ws + 884736);
  float* aff1  = (float*)(ws + 888832);
  float* aff2  = (float*)(ws + 890368);
  float* st1   = (float*)(ws + 891904);
  float* st2   = (float*)(ws + 891968);
  float* part2 = (float*)(ws + 892032);
  short* xn  = (short*)(ws + 1048576);       // 12.58 MB (dead after qkv)
  float* btf = (float*)(ws + 13631488);      // 3.54 MB f32 bias table (dead after attn)
  short* qb  = (short*)(ws + 17301504);      // 12.58 MB (dead after attn)
  short* kb  = (short*)(ws + 29884416);      // 12.58 MB (dead after attn)
  short* vb  = (short*)(ws + 42467328);      // 12.58 MB (dead after attn)
  short* ao  = (short*)(ws + 55050240);      // 12.58 MB (dead after proj)
  float* x1  = (float*)(ws + 1048576);       // 25.17 MB (over xn+btf+qb-head)
  short* x1n = (short*)(ws + 26214400);      // 12.58 MB (over qb-tail+kb-head)
  short* hp  = (short*)(ws + 42467328);      // 33.55 MB (over vb+ao); dw in-place

  cvt_w<<<216, 256, 0, stream>>>(qkv_w, proj_w, fcgv_w, fco_w, wbuf);
  iln_partial<<<512, 256, 0, stream>>>(x, part);
  iln_final<<<2, 256, 0, stream>>>(part, n1_w, n1_b, aff1, st1);
  cvt_aff<<<3072, 256, 0, stream>>>(x, aff1, xn);
  bias_gen<<<216, 256, 0, stream>>>(rpb, btf);
  gemm_qkv<<<dim3(256, 6), 256, 0, stream>>>(xn, wq, qkv_b, qb, kb, vb);
  attn_kernel<<<dim3(128, 6), 256, 0, stream>>>(qb, kb, vb, btf, ao);
  gemm_proj<<<dim3(256, 2), 256, 0, stream>>>(ao, wp, proj_b, x, ls1, st1, x1, part2);
  iln_final<<<2, 256, 0, stream>>>(part2, n2_w, n2_b, aff2, st2);
  cvt_aff<<<3072, 256, 0, stream>>>(x1, aff2, x1n);
  gemm_fcgv<<<dim3(256, 8), 256, 0, stream>>>(x1n, wg, fcgv_b, hp);
  dw_fused<<<1024, 256, 0, stream>>>(hp, dw_w, dw_b, dwd_w, dwd_b, dil, hp);
  gemm_fco<<<dim3(256, 2), 256, 0, stream>>>(hp, wo, fco_b, x1, ls2, st2, out);
}